// Round 2
// baseline (674.914 us; speedup 1.0000x reference)
//
#include <hip/hip_runtime.h>
#include <hip/hip_fp16.h>

// Problem constants
#define BT_N   32768   // B*T queries
#define DDIM   512
#define KCB    4096
#define W_FLAG 0.28f   // fp16-pass gap window (~18 sigma incl. key-quantization bias)
#define W2     0.01f   // refined-pass gap window (20x worst-case refined error)
#define CAP    8192    // max flagged queries handled (expected ~900)
#define NSPLIT 8       // rescan code splits (512 codes each)
#define NSPG   2       // gemm N-splits (4096 / 2048)

typedef _Float16 half8 __attribute__((ext_vector_type(8)));
typedef float    fx4   __attribute__((ext_vector_type(4)));

// ---------------- workspace layout ----------------
static constexpr size_t OFF_XH   = 0;                                // fp16 inputs          32 MB
static constexpr size_t OFF_CH   = OFF_XH   + (size_t)BT_N*DDIM*2;   // fp16 hi(-2c)          4 MB
static constexpr size_t OFF_CL   = OFF_CH   + (size_t)KCB*DDIM*2;    // fp16 lo(-2c)          4 MB
static constexpr size_t OFF_CNP  = OFF_CL   + (size_t)KCB*DDIM*2;    // float  cnorm+1024    16 KB
static constexpr size_t OFF_CND  = OFF_CNP  + (size_t)KCB*4;         // double cnorm         32 KB
static constexpr size_t OFF_V0   = OFF_CND  + (size_t)KCB*8;         // per (split,q) top1 val
static constexpr size_t OFF_I0   = OFF_V0   + (size_t)NSPG*BT_N*4;   // per (split,q) top1 idx
static constexpr size_t OFF_V1   = OFF_I0   + (size_t)NSPG*BT_N*4;   // per (split,q) 2nd val
static constexpr size_t OFF_OIDX = OFF_V1   + (size_t)NSPG*BT_N*4;   // final idx
static constexpr size_t OFF_LIST = OFF_OIDX + (size_t)BT_N*4;        // flagged query list
static constexpr size_t OFF_CNT  = OFF_LIST + (size_t)CAP*4;         // flagged counter
static constexpr size_t OFF_RSV0 = OFF_CNT  + 64;                    // rescan per-split top2
static constexpr size_t OFF_RSI0 = OFF_RSV0 + (size_t)NSPLIT*CAP*4;
static constexpr size_t OFF_RSV1 = OFF_RSI0 + (size_t)NSPLIT*CAP*4;
static constexpr size_t OFF_RSI1 = OFF_RSV1 + (size_t)NSPLIT*CAP*4;

// ---------------- async 16B global->LDS ----------------
__device__ __forceinline__ void async16(const void* g, void* l) {
    __builtin_amdgcn_global_load_lds(
        (const __attribute__((address_space(1))) unsigned int*)g,
        (__attribute__((address_space(3))) unsigned int*)l,
        16, 0, 0);
}

// ---------------- top-2 helpers (smaller-index tie-break, np.argmin semantics) ---
__device__ __forceinline__ void t2_update(float& v0, int& i0, float& v1, int& i1,
                                          float v, int idx) {
    bool t0 = (v < v0) || (v == v0 && idx < i0);
    bool t1 = (v < v1) || (v == v1 && idx < i1);
    float nv1 = t0 ? v0 : (t1 ? v : v1);
    int   ni1 = t0 ? i0 : (t1 ? idx : i1);
    v1 = nv1; i1 = ni1;
    v0 = t0 ? v : v0;
    i0 = t0 ? idx : i0;
}
__device__ __forceinline__ void t2_merge(float& v0, int& i0, float& v1, int& i1,
                                         float ov0, int oi0, float ov1, int oi1) {
    bool oa = (ov0 < v0) || (ov0 == v0 && oi0 < i0);
    float w0 = oa ? ov0 : v0;  int wi0 = oa ? oi0 : i0;
    float l0 = oa ? v0 : ov0;  int li0 = oa ? i0 : oi0;
    float ws = oa ? ov1 : v1;  int wsi = oa ? oi1 : i1;
    bool sb = (l0 < ws) || (l0 == ws && li0 < wsi);
    v0 = w0; i0 = wi0;
    v1 = sb ? l0 : ws; i1 = sb ? li0 : wsi;
}

// ---------------- K_x: convert inputs fp32 -> fp16 ----------------
__global__ __launch_bounds__(256) void vq_cvt_x(const float* __restrict__ X,
                                                _Float16* __restrict__ Xh, int n8) {
    int i = blockIdx.x * 256 + threadIdx.x;
    int stride = gridDim.x * 256;
    for (; i < n8; i += stride) {
        float4 a = ((const float4*)X)[(size_t)i*2];
        float4 b = ((const float4*)X)[(size_t)i*2 + 1];
        half8 h;
        h[0]=(_Float16)a.x; h[1]=(_Float16)a.y; h[2]=(_Float16)a.z; h[3]=(_Float16)a.w;
        h[4]=(_Float16)b.x; h[5]=(_Float16)b.y; h[6]=(_Float16)b.z; h[7]=(_Float16)b.w;
        ((half8*)Xh)[i] = h;
    }
}

// ---------------- K_cb: codebook -> fp16 hi/lo of (-2c), cnorms (4 rows/block) ---
__global__ __launch_bounds__(256) void vq_cvt_cb(const float* __restrict__ CB,
                                                 _Float16* __restrict__ Ch,
                                                 _Float16* __restrict__ Cl,
                                                 float* __restrict__ cnormP,
                                                 double* __restrict__ cnorm_dp) {
    int r = blockIdx.x * 4 + (threadIdx.x >> 6);
    int t = threadIdx.x & 63;
    const float* row = CB + (size_t)r * DDIM;
    float4 a = ((const float4*)row)[t*2];
    float4 b = ((const float4*)row)[t*2 + 1];
    double s = (double)a.x*a.x + (double)a.y*a.y + (double)a.z*a.z + (double)a.w*a.w
             + (double)b.x*b.x + (double)b.y*b.y + (double)b.z*b.z + (double)b.w*b.w;
    float f[8] = {-2.0f*a.x, -2.0f*a.y, -2.0f*a.z, -2.0f*a.w,
                  -2.0f*b.x, -2.0f*b.y, -2.0f*b.z, -2.0f*b.w};
    half8 h, l;
    #pragma unroll
    for (int i = 0; i < 8; ++i) {
        _Float16 hh = (_Float16)f[i];
        h[i] = hh;
        l[i] = (_Float16)(f[i] - (float)hh);
    }
    ((half8*)(Ch + (size_t)r * DDIM))[t] = h;
    ((half8*)(Cl + (size_t)r * DDIM))[t] = l;
    #pragma unroll
    for (int off = 1; off < 64; off <<= 1) s += __shfl_xor(s, off);
    if (t == 0) { cnorm_dp[r] = s; cnormP[r] = (float)(s + 1024.0); }
}

// ---------------- Kernel A: 256x256 8-phase GEMM, nt-continuous pipeline ---------
// 512 thr = 8 waves (2 wave-rows x 4 wave-cols). Per block: 256 queries x 2048
// codes (nt = 8 code-tiles of 256), as 64 CONTINUOUS K-tiles (g = nt*8 + t) so
// the counted-vmcnt pipeline fills once per block. Grid 256 = 1 round on 256 CUs.
// Per K-tile: 4 phases {ds_read frags; stage 1 half-tile; barrier; lgkmcnt(0);
// setprio(1); 16 MFMA; setprio(0); barrier}; stream pos p = half-tile (p%4:
// B.ks0, A.ks0, B.ks1, A.ks1) of tile p>>2; stages at pos 4g+7..4g+10; vmcnt(6)
// once per tile (vmcnt(0) only at final drain). LDS subtiled [group16][q4][row15]
// -> wave ds_read_b128 = 1KB contiguous; global_load_lds dest linear, src
// permuted (verified r1). cnorm panel (2048 f32) stashed in an 8KB LDS side
// region so mid-loop cn reads never touch the vmcnt stream; acc inits to cn.
// Keyed top-2: score > 0 so float bit order == numeric order; low 5 mantissa
// bits carry (nt<<2)|ni (monotone in code index; quantization ~4e-3 << W_FLAG).
__device__ __forceinline__ void stage_a(char* smem, int tid, const _Float16* srcA0,
                                        int g, int ks, int buf) {
    char* d = smem + buf*65536 + ks*16384 + tid*16;
    const _Float16* s = srcA0 + (g & 7)*64 + ks*32;
    async16(s, d);
    async16(s + (size_t)128*DDIM, d + 8192);
}
__device__ __forceinline__ void stage_b(char* smem, int tid, const _Float16* srcB0,
                                        int g, int ks, int buf) {
    char* d = smem + buf*65536 + 32768 + ks*16384 + tid*16;
    const _Float16* s = srcB0 + (size_t)(g >> 3)*(256*DDIM) + (g & 7)*64 + ks*32;
    async16(s, d);
    async16(s + (size_t)128*DDIM, d + 8192);
}

template<int BUFC>
__device__ __forceinline__ void k_iter(int g, bool p1g, bool sg,
                                       const char* abase, const char* bbase,
                                       char* smem, int tid,
                                       const _Float16* srcA0, const _Float16* srcB0,
                                       fx4 (&acc)[8][4]) {
    const char* ab = abase + BUFC*65536;
    const char* bb = bbase + BUFC*65536;
    half8 af[4], bf[4];
    // ---- P1: ks0, mi 0..3 ----
    #pragma unroll
    for (int ni = 0; ni < 4; ++ni) bf[ni] = *(const half8*)(bb + ni*1024);
    #pragma unroll
    for (int mi = 0; mi < 4; ++mi) af[mi] = *(const half8*)(ab + mi*1024);
    if (p1g) stage_a(smem, tid, srcA0, g + 1, 1, BUFC ^ 1);     // pos 4g+7
    __builtin_amdgcn_s_barrier();
    asm volatile("s_waitcnt lgkmcnt(0)" ::: "memory");
    __builtin_amdgcn_sched_barrier(0);
    __builtin_amdgcn_s_setprio(1);
    #pragma unroll
    for (int mi = 0; mi < 4; ++mi)
        #pragma unroll
        for (int ni = 0; ni < 4; ++ni)
            acc[mi][ni] = __builtin_amdgcn_mfma_f32_16x16x32_f16(af[mi], bf[ni], acc[mi][ni], 0, 0, 0);
    __builtin_amdgcn_s_setprio(0);
    __builtin_amdgcn_s_barrier();
    // ---- P2: ks0, mi 4..7 ----
    #pragma unroll
    for (int mi = 0; mi < 4; ++mi) af[mi] = *(const half8*)(ab + (mi + 4)*1024);
    if (sg) stage_b(smem, tid, srcB0, g + 2, 0, BUFC);          // pos 4g+8
    __builtin_amdgcn_s_barrier();
    asm volatile("s_waitcnt lgkmcnt(0)" ::: "memory");
    __builtin_amdgcn_sched_barrier(0);
    __builtin_amdgcn_s_setprio(1);
    #pragma unroll
    for (int mi = 0; mi < 4; ++mi)
        #pragma unroll
        for (int ni = 0; ni < 4; ++ni)
            acc[mi + 4][ni] = __builtin_amdgcn_mfma_f32_16x16x32_f16(af[mi], bf[ni], acc[mi + 4][ni], 0, 0, 0);
    __builtin_amdgcn_s_setprio(0);
    __builtin_amdgcn_s_barrier();
    // ---- P3: ks1, mi 0..3 ----
    #pragma unroll
    for (int ni = 0; ni < 4; ++ni) bf[ni] = *(const half8*)(bb + 16384 + ni*1024);
    #pragma unroll
    for (int mi = 0; mi < 4; ++mi) af[mi] = *(const half8*)(ab + 16384 + mi*1024);
    if (sg) stage_a(smem, tid, srcA0, g + 2, 0, BUFC);          // pos 4g+9
    __builtin_amdgcn_s_barrier();
    asm volatile("s_waitcnt lgkmcnt(0)" ::: "memory");
    __builtin_amdgcn_sched_barrier(0);
    __builtin_amdgcn_s_setprio(1);
    #pragma unroll
    for (int mi = 0; mi < 4; ++mi)
        #pragma unroll
        for (int ni = 0; ni < 4; ++ni)
            acc[mi][ni] = __builtin_amdgcn_mfma_f32_16x16x32_f16(af[mi], bf[ni], acc[mi][ni], 0, 0, 0);
    __builtin_amdgcn_s_setprio(0);
    __builtin_amdgcn_s_barrier();
    // ---- P4: ks1, mi 4..7 ----
    #pragma unroll
    for (int mi = 0; mi < 4; ++mi) af[mi] = *(const half8*)(ab + 16384 + (mi + 4)*1024);
    if (sg) stage_b(smem, tid, srcB0, g + 2, 1, BUFC);          // pos 4g+10
    __builtin_amdgcn_s_barrier();
    asm volatile("s_waitcnt lgkmcnt(0)" ::: "memory");
    __builtin_amdgcn_sched_barrier(0);
    __builtin_amdgcn_s_setprio(1);
    #pragma unroll
    for (int mi = 0; mi < 4; ++mi)
        #pragma unroll
        for (int ni = 0; ni < 4; ++ni)
            acc[mi + 4][ni] = __builtin_amdgcn_mfma_f32_16x16x32_f16(af[mi], bf[ni], acc[mi + 4][ni], 0, 0, 0);
    __builtin_amdgcn_s_setprio(0);
    // caller emits vmcnt + final barrier
}

__global__ __launch_bounds__(512, 2) void vq_gemm(
    const _Float16* __restrict__ Xh, const _Float16* __restrict__ Ch,
    const float* __restrict__ cnormP,
    float* __restrict__ ws_v0, int* __restrict__ ws_i0, float* __restrict__ ws_v1)
{
    __shared__ ulonglong2 smem_u[8704];   // 128KB tiles + 8KB cnorm stash
    char* smem = (char*)smem_u;
    float* cn_lds = (float*)(smem + 131072);

    const int tid  = threadIdx.x;
    const int wid  = tid >> 6;
    const int lane = tid & 63;
    const int c16  = lane & 15;
    const int q4   = lane >> 4;
    const int wm   = wid >> 2;      // 0..1
    const int wn   = wid & 3;       // 0..3

    const int bid   = blockIdx.x;
    const int swz   = (bid & 7) * 32 + (bid >> 3);   // XCD swizzle (256 % 8 == 0)
    const int m0    = (swz >> 1) * 256;
    const int split = swz & 1;
    const int n0    = split * 2048;

    const _Float16* srcA0 = Xh + (size_t)(m0 + wid*16 + c16) * DDIM + q4*8;
    const _Float16* srcB0 = Ch + (size_t)(n0 + wid*16 + c16) * DDIM + q4*8;

    // frag-read bases: LDS elem (row,chunk q) at group*1024 + q*256 + (row&15)*16
    const int aoff = q4*256 + c16*16;
    const char* abase = smem + wm*8192 + aoff;            // A groups wm*8 + mi
    const char* bbase = smem + 32768 + wn*4096 + aoff;    // B groups wn*4 + ni

    // ---- prologue: cnorm stash (drained BEFORE the counted stream starts) ----
    float4 cnld = ((const float4*)(cnormP + n0))[tid];
    asm volatile("s_waitcnt vmcnt(0)" ::: "memory");
    ((float4*)cn_lds)[tid] = cnld;

    // stage half-tile stream positions 0..6 (tile0 complete, tile1 minus A.ks1)
    stage_b(smem, tid, srcB0, 0, 0, 0);
    stage_a(smem, tid, srcA0, 0, 0, 0);
    stage_b(smem, tid, srcB0, 0, 1, 0);
    stage_a(smem, tid, srcA0, 0, 1, 0);
    stage_b(smem, tid, srcB0, 1, 0, 1);
    stage_a(smem, tid, srcA0, 1, 0, 1);
    stage_b(smem, tid, srcB0, 1, 1, 1);

    asm volatile("s_waitcnt lgkmcnt(0)" ::: "memory");   // cn ds_write done
    __builtin_amdgcn_s_barrier();                        // cn stash visible to all

    float k0[8][4], k1[8][4];
    #pragma unroll
    for (int mi = 0; mi < 8; ++mi)
        #pragma unroll
        for (int j = 0; j < 4; ++j) { k0[mi][j] = 3e38f; k1[mi][j] = 3e38f; }

    fx4 acc[8][4];
    {
        float cnv[4];
        #pragma unroll
        for (int ni = 0; ni < 4; ++ni) cnv[ni] = cn_lds[wn*64 + ni*16 + c16];
        #pragma unroll
        for (int mi = 0; mi < 8; ++mi)
            #pragma unroll
            for (int ni = 0; ni < 4; ++ni)
                acc[mi][ni] = (fx4){cnv[ni], cnv[ni], cnv[ni], cnv[ni]};
    }

    asm volatile("s_waitcnt vmcnt(6)" ::: "memory");     // tile 0 resident
    __builtin_amdgcn_s_barrier();

    #pragma unroll 1
    for (int gp = 0; gp < 32; ++gp) {
        const bool sg = (gp < 31);
        // even tile g = 2*gp (buffer 0)
        k_iter<0>(2*gp, true, sg, abase, bbase, smem, tid, srcA0, srcB0, acc);
        if (sg) asm volatile("s_waitcnt vmcnt(6)" ::: "memory");
        else    asm volatile("s_waitcnt vmcnt(0)" ::: "memory");   // g=62: final drain
        __builtin_amdgcn_s_barrier();
        // odd tile g = 2*gp+1 (buffer 1)
        k_iter<1>(2*gp + 1, sg, sg, abase, bbase, smem, tid, srcA0, srcB0, acc);
        if (sg) asm volatile("s_waitcnt vmcnt(6)" ::: "memory");
        __builtin_amdgcn_s_barrier();
        // keyed top-2 fold every 8 K-tiles (nt complete); registers only
        if ((gp & 3) == 3) {
            const int nt = (2*gp + 1) >> 3;
            #pragma unroll
            for (int ni = 0; ni < 4; ++ni) {
                const int idx5 = (nt << 2) | ni;
                #pragma unroll
                for (int mi = 0; mi < 8; ++mi)
                    #pragma unroll
                    for (int j = 0; j < 4; ++j) {
                        float key = __int_as_float(
                            (__float_as_int(acc[mi][ni][j]) & 0xFFFFFFE0) | idx5);
                        k1[mi][j] = __builtin_amdgcn_fmed3f(key, k0[mi][j], k1[mi][j]);
                        k0[mi][j] = fminf(k0[mi][j], key);
                    }
            }
            const int ntn = nt + 1;
            if (ntn < 8) {
                float cnv[4];
                #pragma unroll
                for (int ni = 0; ni < 4; ++ni)
                    cnv[ni] = cn_lds[ntn*256 + wn*64 + ni*16 + c16];
                #pragma unroll
                for (int mi = 0; mi < 8; ++mi)
                    #pragma unroll
                    for (int ni = 0; ni < 4; ++ni)
                        acc[mi][ni] = (fx4){cnv[ni], cnv[ni], cnv[ni], cnv[ni]};
            }
        }
    }

    // ---------- epilogue (once per block) ----------
    // unpack keys -> (v0, idx, v1), butterfly across the 16 c16 lanes
    float v0[8][4], v1[8][4]; int i0a[8][4];
    #pragma unroll
    for (int mi = 0; mi < 8; ++mi)
        #pragma unroll
        for (int j = 0; j < 4; ++j) {
            int b = __float_as_int(k0[mi][j]);
            int idx5 = b & 31;
            i0a[mi][j] = n0 + (idx5 >> 2)*256 + wn*64 + (idx5 & 3)*16 + c16;
            v0[mi][j]  = __int_as_float(b & 0xFFFFFFE0);
            v1[mi][j]  = __int_as_float(__float_as_int(k1[mi][j]) & 0xFFFFFFE0);
        }
    #pragma unroll
    for (int off = 1; off < 16; off <<= 1)
        #pragma unroll
        for (int mi = 0; mi < 8; ++mi)
            #pragma unroll
            for (int j = 0; j < 4; ++j) {
                float ov0 = __shfl_xor(v0[mi][j], off);
                int   oi0 = __shfl_xor(i0a[mi][j], off);
                float ov1 = __shfl_xor(v1[mi][j], off);
                float nv1 = fminf(fmaxf(v0[mi][j], ov0), fminf(v1[mi][j], ov1));
                bool take = (ov0 < v0[mi][j]) || (ov0 == v0[mi][j] && oi0 < i0a[mi][j]);
                v0[mi][j]  = take ? ov0 : v0[mi][j];
                i0a[mi][j] = take ? oi0 : i0a[mi][j];
                v1[mi][j]  = nv1;
            }

    // cross-wave (wn) merge through LDS (tiles are dead; all loads drained)
    float* ev0 = (float*)smem;            // [256][4]
    int*   ei0 = (int*)(smem + 4096);
    float* ev1 = (float*)(smem + 8192);
    if (c16 == 0) {
        #pragma unroll
        for (int mi = 0; mi < 8; ++mi)
            #pragma unroll
            for (int j = 0; j < 4; ++j) {
                int r = wm*128 + mi*16 + q4*4 + j;
                ev0[r*4 + wn] = v0[mi][j];
                ei0[r*4 + wn] = i0a[mi][j];
                ev1[r*4 + wn] = v1[mi][j];
            }
    }
    __syncthreads();
    if (tid < 256) {
        float a0 = ev0[tid*4], a1 = ev1[tid*4]; int ai = ei0[tid*4];
        #pragma unroll
        for (int wc = 1; wc < 4; ++wc) {
            float b0 = ev0[tid*4 + wc], b1 = ev1[tid*4 + wc]; int bi = ei0[tid*4 + wc];
            float nv1 = fminf(fmaxf(a0, b0), fminf(a1, b1));
            bool take = (b0 < a0) || (b0 == a0 && bi < ai);
            a0 = take ? b0 : a0; ai = take ? bi : ai; a1 = nv1;
        }
        size_t o = (size_t)split * BT_N + m0 + tid;
        ws_v0[o] = a0; ws_i0[o] = ai; ws_v1[o] = a1;
    }
}

// ---------------- Kernel M: merge splits, flag close calls ----------------
__global__ __launch_bounds__(256) void vq_merge(
    const float* __restrict__ ws_v0, const int* __restrict__ ws_i0, const float* __restrict__ ws_v1,
    int* __restrict__ out_idx, int* __restrict__ list, unsigned int* __restrict__ counter)
{
    int q = blockIdx.x * 256 + threadIdx.x;
    float v0 = ws_v0[q]; int i0 = ws_i0[q]; float v1 = ws_v1[q];
    #pragma unroll
    for (int s = 1; s < NSPG; ++s) {
        size_t o = (size_t)s * BT_N + q;
        float sv0 = ws_v0[o]; int si0 = ws_i0[o]; float sv1 = ws_v1[o];
        v1 = fminf(fmaxf(v0, sv0), fminf(v1, sv1));
        bool take = (sv0 < v0) || (sv0 == v0 && si0 < i0);
        if (take) { v0 = sv0; i0 = si0; }
    }
    if (v1 - v0 < W_FLAG) {
        unsigned int pos = atomicAdd(counter, 1u);
        if (pos < CAP) { list[pos] = q; out_idx[q] = -1; }
        else           { out_idx[q] = i0; }       // graceful degradation (never hit)
    } else {
        out_idx[q] = i0;
    }
}

// ---------------- Kernel R: hi/lo fp16 MFMA rescan of flagged rows over all codes --
__global__ __launch_bounds__(256) void vq_rescan(
    const float* __restrict__ X,
    const _Float16* __restrict__ Ch, const _Float16* __restrict__ Cl,
    const float* __restrict__ cnormP,
    const int* __restrict__ list, const unsigned int* __restrict__ counter,
    float* __restrict__ rs_v0, int* __restrict__ rs_i0,
    float* __restrict__ rs_v1, int* __restrict__ rs_i1)
{
    int mcnt = min((int)*counter, CAP);
    const int m0 = blockIdx.x * 64;
    if (m0 >= mcnt) return;
    const int split = blockIdx.y;
    const int nbase = split * 512;

    __shared__ _Float16 Ah[64][72], Al[64][72];
    __shared__ _Float16 Bh[128][72], Bl[128][72];
    __shared__ int   qr[64];
    __shared__ float e_v0[64][4]; __shared__ int e_i0[64][4];
    __shared__ float e_v1[64][4]; __shared__ int e_i1[64][4];

    const int tid  = threadIdx.x;
    const int lane = tid & 63;
    const int w    = tid >> 6;
    const int c16  = lane & 15;
    const int q4   = lane >> 4;

    if (tid < 64) qr[tid] = list[min(m0 + tid, mcnt - 1)];
    __syncthreads();

    const int ar = tid >> 2;
    const int ac = (tid & 3) << 4;
    const size_t asrc_row = (size_t)qr[ar] * DDIM;

    float t2v0[4][4], t2v1[4][4]; int t2i0[4][4], t2i1[4][4];
    #pragma unroll
    for (int a = 0; a < 4; a++)
        #pragma unroll
        for (int b = 0; b < 4; b++) {
            t2v0[a][b] = 3e38f; t2v1[a][b] = 3e38f;
            t2i0[a][b] = 0x7fffffff; t2i1[a][b] = 0x7fffffff;
        }

    for (int nt = 0; nt < 4; ++nt) {
        const int nb = nbase + nt * 128;
        fx4 acc[4][2];
        #pragma unroll
        for (int mi = 0; mi < 4; ++mi)
            #pragma unroll
            for (int ni = 0; ni < 2; ++ni) acc[mi][ni] = (fx4){0.f, 0.f, 0.f, 0.f};

        for (int kb = 0; kb < DDIM; kb += 64) {
            {
                const float4* s4 = (const float4*)(X + asrc_row + kb + ac);
                float4 f0 = s4[0], f1 = s4[1], f2 = s4[2], f3 = s4[3];
                float fv[16] = {f0.x,f0.y,f0.z,f0.w, f1.x,f1.y,f1.z,f1.w,
                                f2.x,f2.y,f2.z,f2.w, f3.x,f3.y,f3.z,f3.w};
                half8 h0, l0, h1, l1;
                #pragma unroll
                for (int i = 0; i < 8; ++i) {
                    _Float16 hh = (_Float16)fv[i];
                    h0[i] = hh; l0[i] = (_Float16)(fv[i] - (float)hh);
                    _Float16 hh2 = (_Float16)fv[8+i];
                    h1[i] = hh2; l1[i] = (_Float16)(fv[8+i] - (float)hh2);
                }
                *(half8*)&Ah[ar][ac]     = h0;  *(half8*)&Ah[ar][ac + 8] = h1;
                *(half8*)&Al[ar][ac]     = l0;  *(half8*)&Al[ar][ac + 8] = l1;
            }
            #pragma unroll
            for (int g = 0; g < 4; ++g) {
                int li = g * 256 + tid;
                int br = li >> 3, bs = (li & 7) << 3;
                size_t src = (size_t)(nb + br) * DDIM + kb + bs;
                *(half8*)&Bh[br][bs] = *(const half8*)(Ch + src);
                *(half8*)&Bl[br][bs] = *(const half8*)(Cl + src);
            }
            __syncthreads();
            #pragma unroll
            for (int kk = 0; kk < 2; ++kk) {
                const int col = kk * 32 + q4 * 8;
                half8 ahf[4], alf[4], bhf[2], blf[2];
                #pragma unroll
                for (int mi = 0; mi < 4; ++mi) {
                    ahf[mi] = *(const half8*)&Ah[mi * 16 + c16][col];
                    alf[mi] = *(const half8*)&Al[mi * 16 + c16][col];
                }
                #pragma unroll
                for (int ni = 0; ni < 2; ++ni) {
                    int br = w * 32 + ni * 16 + c16;
                    bhf[ni] = *(const half8*)&Bh[br][col];
                    blf[ni] = *(const half8*)&Bl[br][col];
                }
                #pragma unroll
                for (int mi = 0; mi < 4; ++mi)
                    #pragma unroll
                    for (int ni = 0; ni < 2; ++ni) {
                        acc[mi][ni] = __builtin_amdgcn_mfma_f32_16x16x32_f16(ahf[mi], bhf[ni], acc[mi][ni], 0, 0, 0);
                        acc[mi][ni] = __builtin_amdgcn_mfma_f32_16x16x32_f16(ahf[mi], blf[ni], acc[mi][ni], 0, 0, 0);
                        acc[mi][ni] = __builtin_amdgcn_mfma_f32_16x16x32_f16(alf[mi], bhf[ni], acc[mi][ni], 0, 0, 0);
                    }
            }
            __syncthreads();
        }
        #pragma unroll
        for (int ni = 0; ni < 2; ++ni) {
            int code = nb + w * 32 + ni * 16 + c16;
            float cn = cnormP[code];
            #pragma unroll
            for (int mi = 0; mi < 4; ++mi)
                #pragma unroll
                for (int j = 0; j < 4; ++j)
                    t2_update(t2v0[mi][j], t2i0[mi][j], t2v1[mi][j], t2i1[mi][j],
                              acc[mi][ni][j] + cn, code);
        }
    }

    #pragma unroll
    for (int off = 1; off < 16; off <<= 1) {
        #pragma unroll
        for (int mi = 0; mi < 4; ++mi)
            #pragma unroll
            for (int j = 0; j < 4; ++j) {
                float ov0 = __shfl_xor(t2v0[mi][j], off);
                int   oi0 = __shfl_xor(t2i0[mi][j], off);
                float ov1 = __shfl_xor(t2v1[mi][j], off);
                int   oi1 = __shfl_xor(t2i1[mi][j], off);
                t2_merge(t2v0[mi][j], t2i0[mi][j], t2v1[mi][j], t2i1[mi][j],
                         ov0, oi0, ov1, oi1);
            }
    }
    if (c16 == 0) {
        #pragma unroll
        for (int mi = 0; mi < 4; ++mi)
            #pragma unroll
            for (int j = 0; j < 4; ++j) {
                int r = mi * 16 + q4 * 4 + j;
                e_v0[r][w] = t2v0[mi][j]; e_i0[r][w] = t2i0[mi][j];
                e_v1[r][w] = t2v1[mi][j]; e_i1[r][w] = t2i1[mi][j];
            }
    }
    __syncthreads();
    if (tid < 64 && m0 + tid < mcnt) {
        float v0 = e_v0[tid][0], v1 = e_v1[tid][0];
        int   i0 = e_i0[tid][0], i1 = e_i1[tid][0];
        #pragma unroll
        for (int wc = 1; wc < 4; ++wc)
            t2_merge(v0, i0, v1, i1, e_v0[tid][wc], e_i0[tid][wc], e_v1[tid][wc], e_i1[tid][wc]);
        size_t o = (size_t)split * CAP + m0 + tid;
        rs_v0[o] = v0; rs_i0[o] = i0; rs_v1[o] = v1; rs_i1[o] = i1;
    }
}

// ---------------- Kernel M2: merge rescan splits; wave-cooperative fp64 verdict --
__global__ __launch_bounds__(256) void vq_merge2(
    const float* __restrict__ X, const float* __restrict__ CB,
    const int* __restrict__ list, const unsigned int* __restrict__ counter,
    const float* __restrict__ rs_v0, const int* __restrict__ rs_i0,
    const float* __restrict__ rs_v1, const int* __restrict__ rs_i1,
    int* __restrict__ out_idx)
{
    int cnt = min((int)*counter, CAP);
    int m = blockIdx.x * 256 + threadIdx.x;
    const int lane = threadIdx.x & 63;
    bool active = m < cnt;
    int q = 0;
    float v0 = 3e38f, v1 = 3e38f; int i0 = 0x7fffffff, i1 = 0x7fffffff;
    if (active) {
        q = list[m];
        #pragma unroll
        for (int s = 0; s < NSPLIT; ++s) {
            size_t o = (size_t)s * CAP + m;
            t2_merge(v0, i0, v1, i1, rs_v0[o], rs_i0[o], rs_v1[o], rs_i1[o]);
        }
    }
    int pick = i0;
    unsigned long long need = __ballot(active && (v1 - v0 < W2));
    while (need) {
        int src = __ffsll((long long)need) - 1;
        need &= need - 1;
        int qq = __shfl(q, src), a = __shfl(i0, src), b = __shfl(i1, src);
        const float* xr  = X  + (size_t)qq * DDIM + lane * 8;
        const float* c0p = CB + (size_t)a  * DDIM + lane * 8;
        const float* c1p = CB + (size_t)b  * DDIM + lane * 8;
        double d0 = 0.0, d1 = 0.0;
        #pragma unroll
        for (int j = 0; j < 8; ++j) {
            double xv = (double)xr[j];
            double e0 = xv - (double)c0p[j]; d0 = fma(e0, e0, d0);
            double e1 = xv - (double)c1p[j]; d1 = fma(e1, e1, d1);
        }
        #pragma unroll
        for (int off = 1; off < 64; off <<= 1) {
            d0 += __shfl_xor(d0, off);
            d1 += __shfl_xor(d1, off);
        }
        if (lane == src) {
            bool tb = (d1 < d0) || (d1 == d0 && b < a);
            pick = tb ? b : a;
        }
    }
    if (active) out_idx[q] = pick;
}

// ---------------- Kernel G: gather codebook rows (wave per query) ----------------
__global__ __launch_bounds__(256) void vq_gather(
    const float* __restrict__ CB, const int* __restrict__ out_idx,
    float* __restrict__ out)
{
    const int wave = (blockIdx.x * 256 + threadIdx.x) >> 6;   // 0..4095
    const int lane = threadIdx.x & 63;
    for (int q = wave; q < BT_N; q += 4096) {
        int idx = out_idx[q];
        const float4* src = (const float4*)(CB + (size_t)idx * DDIM);
        float4* dst = (float4*)(out + (size_t)q * DDIM);
        dst[lane]      = src[lane];
        dst[lane + 64] = src[lane + 64];
    }
}

// ---------------- launcher ----------------
extern "C" void kernel_launch(void* const* d_in, const int* in_sizes, int n_in,
                              void* d_out, int out_size, void* d_ws, size_t ws_size,
                              hipStream_t stream) {
    const float* X  = (const float*)d_in[0];   // [32768,512]
    const float* CB = (const float*)d_in[1];   // [4096,512]
    float* out = (float*)d_out;

    char* ws = (char*)d_ws;
    _Float16* Xh       = (_Float16*)(ws + OFF_XH);
    _Float16* Ch       = (_Float16*)(ws + OFF_CH);
    _Float16* Cl       = (_Float16*)(ws + OFF_CL);
    float*    cnormP   = (float*)(ws + OFF_CNP);
    double*   cnorm_dp = (double*)(ws + OFF_CND);
    float*    ws_v0    = (float*)(ws + OFF_V0);
    int*      ws_i0    = (int*)(ws + OFF_I0);
    float*    ws_v1    = (float*)(ws + OFF_V1);
    int*      out_idx  = (int*)(ws + OFF_OIDX);
    int*      list     = (int*)(ws + OFF_LIST);
    unsigned int* counter = (unsigned int*)(ws + OFF_CNT);
    float*    rs_v0    = (float*)(ws + OFF_RSV0);
    int*      rs_i0    = (int*)(ws + OFF_RSI0);
    float*    rs_v1    = (float*)(ws + OFF_RSV1);
    int*      rs_i1    = (int*)(ws + OFF_RSI1);

    hipMemsetAsync(counter, 0, 4, stream);
    vq_cvt_x<<<2048, 256, 0, stream>>>(X, Xh, BT_N * DDIM / 8);
    vq_cvt_cb<<<KCB / 4, 256, 0, stream>>>(CB, Ch, Cl, cnormP, cnorm_dp);
    vq_gemm<<<256, 512, 0, stream>>>(Xh, Ch, cnormP, ws_v0, ws_i0, ws_v1);
    vq_merge<<<BT_N / 256, 256, 0, stream>>>(ws_v0, ws_i0, ws_v1, out_idx, list, counter);
    vq_rescan<<<dim3(CAP / 64, NSPLIT), 256, 0, stream>>>(X, Ch, Cl, cnormP, list, counter,
                                                          rs_v0, rs_i0, rs_v1, rs_i1);
    vq_merge2<<<CAP / 256, 256, 0, stream>>>(X, CB, list, counter,
                                             rs_v0, rs_i0, rs_v1, rs_i1, out_idx);
    vq_gather<<<1024, 256, 0, stream>>>(CB, out_idx, out);
}

// Round 4
// 491.261 us; speedup vs baseline: 1.3738x; 1.3738x over previous
//
#include <hip/hip_runtime.h>
#include <hip/hip_fp16.h>

// Problem constants
#define BT_N   32768   // B*T queries
#define DDIM   512
#define KCB    4096
#define W_FLAG 0.28f   // fp16-pass gap window (~18 sigma incl. key-quantization bias)
#define W2     0.01f   // refined-pass gap window (20x worst-case refined error)
#define CAP    8192    // max flagged queries handled (expected ~900)
#define NSPLIT 8       // rescan code splits (512 codes each)
#define NSPG   2       // gemm N-splits (4096 / 2048)

typedef _Float16 half8 __attribute__((ext_vector_type(8)));
typedef float    fx4   __attribute__((ext_vector_type(4)));

// ---------------- workspace layout ----------------
static constexpr size_t OFF_XH   = 0;                                // fp16 inputs          32 MB
static constexpr size_t OFF_CH   = OFF_XH   + (size_t)BT_N*DDIM*2;   // fp16 hi(-2c)          4 MB
static constexpr size_t OFF_CL   = OFF_CH   + (size_t)KCB*DDIM*2;    // fp16 lo(-2c)          4 MB
static constexpr size_t OFF_CNP  = OFF_CL   + (size_t)KCB*DDIM*2;    // float  cnorm+1024    16 KB
static constexpr size_t OFF_CND  = OFF_CNP  + (size_t)KCB*4;         // double cnorm         32 KB
static constexpr size_t OFF_V0   = OFF_CND  + (size_t)KCB*8;         // per (split,q) top1 val
static constexpr size_t OFF_I0   = OFF_V0   + (size_t)NSPG*BT_N*4;   // per (split,q) top1 idx
static constexpr size_t OFF_V1   = OFF_I0   + (size_t)NSPG*BT_N*4;   // per (split,q) 2nd val
static constexpr size_t OFF_OIDX = OFF_V1   + (size_t)NSPG*BT_N*4;   // final idx
static constexpr size_t OFF_LIST = OFF_OIDX + (size_t)BT_N*4;        // flagged query list
static constexpr size_t OFF_CNT  = OFF_LIST + (size_t)CAP*4;         // flagged counter
static constexpr size_t OFF_RSV0 = OFF_CNT  + 64;                    // rescan per-split top2
static constexpr size_t OFF_RSI0 = OFF_RSV0 + (size_t)NSPLIT*CAP*4;
static constexpr size_t OFF_RSV1 = OFF_RSI0 + (size_t)NSPLIT*CAP*4;
static constexpr size_t OFF_RSI1 = OFF_RSV1 + (size_t)NSPLIT*CAP*4;

// ---------------- async 16B global->LDS ----------------
__device__ __forceinline__ void async16(const void* g, void* l) {
    __builtin_amdgcn_global_load_lds(
        (const __attribute__((address_space(1))) unsigned int*)g,
        (__attribute__((address_space(3))) unsigned int*)l,
        16, 0, 0);
}

// ---------------- top-2 helpers (smaller-index tie-break, np.argmin semantics) ---
__device__ __forceinline__ void t2_update(float& v0, int& i0, float& v1, int& i1,
                                          float v, int idx) {
    bool t0 = (v < v0) || (v == v0 && idx < i0);
    bool t1 = (v < v1) || (v == v1 && idx < i1);
    float nv1 = t0 ? v0 : (t1 ? v : v1);
    int   ni1 = t0 ? i0 : (t1 ? idx : i1);
    v1 = nv1; i1 = ni1;
    v0 = t0 ? v : v0;
    i0 = t0 ? idx : i0;
}
__device__ __forceinline__ void t2_merge(float& v0, int& i0, float& v1, int& i1,
                                         float ov0, int oi0, float ov1, int oi1) {
    bool oa = (ov0 < v0) || (ov0 == v0 && oi0 < i0);
    float w0 = oa ? ov0 : v0;  int wi0 = oa ? oi0 : i0;
    float l0 = oa ? v0 : ov0;  int li0 = oa ? i0 : oi0;
    float ws = oa ? ov1 : v1;  int wsi = oa ? oi1 : i1;
    bool sb = (l0 < ws) || (l0 == ws && li0 < wsi);
    v0 = w0; i0 = wi0;
    v1 = sb ? l0 : ws; i1 = sb ? li0 : wsi;
}

// ---------------- K_x: convert inputs fp32 -> fp16 ----------------
__global__ __launch_bounds__(256) void vq_cvt_x(const float* __restrict__ X,
                                                _Float16* __restrict__ Xh, int n8) {
    int i = blockIdx.x * 256 + threadIdx.x;
    int stride = gridDim.x * 256;
    for (; i < n8; i += stride) {
        float4 a = ((const float4*)X)[(size_t)i*2];
        float4 b = ((const float4*)X)[(size_t)i*2 + 1];
        half8 h;
        h[0]=(_Float16)a.x; h[1]=(_Float16)a.y; h[2]=(_Float16)a.z; h[3]=(_Float16)a.w;
        h[4]=(_Float16)b.x; h[5]=(_Float16)b.y; h[6]=(_Float16)b.z; h[7]=(_Float16)b.w;
        ((half8*)Xh)[i] = h;
    }
}

// ---------------- K_cb: codebook -> fp16 hi/lo of (-2c), cnorms (4 rows/block) ---
__global__ __launch_bounds__(256) void vq_cvt_cb(const float* __restrict__ CB,
                                                 _Float16* __restrict__ Ch,
                                                 _Float16* __restrict__ Cl,
                                                 float* __restrict__ cnormP,
                                                 double* __restrict__ cnorm_dp) {
    int r = blockIdx.x * 4 + (threadIdx.x >> 6);
    int t = threadIdx.x & 63;
    const float* row = CB + (size_t)r * DDIM;
    float4 a = ((const float4*)row)[t*2];
    float4 b = ((const float4*)row)[t*2 + 1];
    double s = (double)a.x*a.x + (double)a.y*a.y + (double)a.z*a.z + (double)a.w*a.w
             + (double)b.x*b.x + (double)b.y*b.y + (double)b.z*b.z + (double)b.w*b.w;
    float f[8] = {-2.0f*a.x, -2.0f*a.y, -2.0f*a.z, -2.0f*a.w,
                  -2.0f*b.x, -2.0f*b.y, -2.0f*b.z, -2.0f*b.w};
    half8 h, l;
    #pragma unroll
    for (int i = 0; i < 8; ++i) {
        _Float16 hh = (_Float16)f[i];
        h[i] = hh;
        l[i] = (_Float16)(f[i] - (float)hh);
    }
    ((half8*)(Ch + (size_t)r * DDIM))[t] = h;
    ((half8*)(Cl + (size_t)r * DDIM))[t] = l;
    #pragma unroll
    for (int off = 1; off < 64; off <<= 1) s += __shfl_xor(s, off);
    if (t == 0) { cnorm_dp[r] = s; cnormP[r] = (float)(s + 1024.0); }
}

// ---------------- Kernel A: 128x256-tile continuous-pipeline GEMM + keyed top-2 --
// 512 thr = 8 waves (2M x 4N), wave owns 64x64 -> acc[4][4] (64 VGPR), keys
// k0/k1[4][4] (32 VGPR): total ~150 regs, NO spill (round-2 failure mode).
// Per block: 128 queries x 2048 codes (split), 8 nt x 8 kt = 64 CONTINUOUS
// K-tiles = 128 phases; grid 512 = 2 rounds. Phase P reads (tile T=P>>1, ks=P&1):
//   { vmcnt(6); s_barrier; stage region for phase P+3 (A 1 + B 2 issues);
//     8x ds_read_b128; lgkmcnt(0); sched_barrier; setprio(1); 16 MFMA; setprio(0) }
// Race-safety: region staged at P was last read at P-1; P's barrier post-dates
// those reads (retired before P-1's MFMA via lgkmcnt(0)). vmcnt(6) with 9 issues
// outstanding retires exactly the current region's 3 loads; tail uses 3/0.
// LDS subtiled [group16][q4][row15]: wave ds_read_b128 = 1KB contiguous
// (conflict-free); global_load_lds dest linear, source carries the permutation
// (verified r1/r2). cnorm panel stashed in LDS so mid-loop reads never touch the
// vmcnt stream. Keys: score = cnorm+1024-2x.c > 0 -> float bit order == numeric
// order; low 5 mantissa bits carry (nt<<2)|ni (monotone in code index;
// quantization ~8e-3 << W_FLAG) -- identical semantics to the 474us baseline.
__global__ __launch_bounds__(512, 2) void vq_gemm(
    const _Float16* __restrict__ Xh, const _Float16* __restrict__ Ch,
    const float* __restrict__ cnormP,
    float* __restrict__ ws_v0, int* __restrict__ ws_i0, float* __restrict__ ws_v1)
{
    __shared__ ulonglong2 smem_u[106496/16];   // 2buf x (A 16KB + B 32KB) + 8KB cn
    char* smem = (char*)smem_u;
    float* cn_lds = (float*)(smem + 98304);

    const int tid  = threadIdx.x;
    const int wid  = tid >> 6;
    const int lane = tid & 63;
    const int c16  = lane & 15;
    const int q4   = lane >> 4;
    const int wm   = wid >> 2;      // 0..1  (M half)
    const int wn   = wid & 3;       // 0..3  (N quarter)

    const int bid   = blockIdx.x;
    const int mblk  = bid >> 1;
    const int split = bid & 1;
    const int m0    = mblk * 128;
    const int n0    = split * 2048;

    // staging sources: thread t covers (row = (t>>6)*16 + (t&15), colchunk = (t>>4)&3)
    const int srow = ((tid >> 6) << 4) + (tid & 15);
    const int scol = ((tid >> 4) & 3) * 8;
    const _Float16* srcA0 = Xh + (size_t)(m0 + srow) * DDIM + scol;
    const _Float16* srcB0 = Ch + (size_t)(n0 + srow) * DDIM + scol;

    // frag-read offsets: LDS elem (row,chunk q) at group*1024 + q*256 + (row&15)*16
    const int aoff = wm*4096 + q4*256 + c16*16;   // A group = wm*4 + mi
    const int boff = wn*4096 + q4*256 + c16*16;   // B group = wn*4 + ni

    // region for (tile TS, ks): staged as A(1 issue) + B(2 issues) = 3 issues
#define STAGE_TO(TS, KSD, BUFD) do {                                            \
    const int _ts = (TS);                                                       \
    const int _off = (_ts & 7)*64 + (KSD)*32;                                   \
    char* _ad = smem + (BUFD)*49152 + (KSD)*8192 + tid*16;                      \
    char* _bd = smem + (BUFD)*49152 + 16384 + (KSD)*16384 + tid*16;             \
    async16(srcA0 + _off, _ad);                                                 \
    const _Float16* _bs = srcB0 + (size_t)(_ts >> 3)*(256*DDIM) + _off;         \
    async16(_bs, _bd);                                                          \
    async16(_bs + 128*DDIM, _bd + 8192);                                        \
} while (0)

#define PH(BUF, KS, VMSTR, DOSTAGE, TS, KSD, BUFD) do {                         \
    asm volatile("s_waitcnt " VMSTR ::: "memory");                              \
    __builtin_amdgcn_s_barrier();                                               \
    if (DOSTAGE) STAGE_TO(TS, KSD, BUFD);                                       \
    const char* _ab = smem + (BUF)*49152 + (KS)*8192 + aoff;                    \
    const char* _bb = smem + (BUF)*49152 + 16384 + (KS)*16384 + boff;           \
    half8 af[4], bf[4];                                                         \
    _Pragma("unroll")                                                           \
    for (int mi = 0; mi < 4; ++mi) af[mi] = *(const half8*)(_ab + mi*1024);     \
    _Pragma("unroll")                                                           \
    for (int ni = 0; ni < 4; ++ni) bf[ni] = *(const half8*)(_bb + ni*1024);     \
    asm volatile("s_waitcnt lgkmcnt(0)" ::: "memory");                          \
    __builtin_amdgcn_sched_barrier(0);                                          \
    __builtin_amdgcn_s_setprio(1);                                              \
    _Pragma("unroll")                                                           \
    for (int mi = 0; mi < 4; ++mi)                                              \
        _Pragma("unroll")                                                       \
        for (int ni = 0; ni < 4; ++ni)                                          \
            acc[mi][ni] = __builtin_amdgcn_mfma_f32_16x16x32_f16(af[mi], bf[ni], acc[mi][ni], 0, 0, 0); \
    __builtin_amdgcn_s_setprio(0);                                              \
} while (0)

    // ---- prologue: cnorm stash, drained before the counted stream starts ----
    float4 cnld = ((const float4*)(cnormP + n0))[tid];   // 512 x 16B = 8KB
    asm volatile("s_waitcnt vmcnt(0)" ::: "memory");
    ((float4*)cn_lds)[tid] = cnld;

    // stage regions for phases 0,1,2: (t0,ks0,b0), (t0,ks1,b0), (t1,ks0,b1) = 9 issues
    STAGE_TO(0, 0, 0);
    STAGE_TO(0, 1, 0);
    STAGE_TO(1, 0, 1);

    asm volatile("s_waitcnt lgkmcnt(0)" ::: "memory");   // cn ds_write done
    __builtin_amdgcn_s_barrier();                        // cn stash visible

    float k0[4][4], k1[4][4];
    #pragma unroll
    for (int mi = 0; mi < 4; ++mi)
        #pragma unroll
        for (int j = 0; j < 4; ++j) { k0[mi][j] = 3e38f; k1[mi][j] = 3e38f; }

    fx4 acc[4][4];
    {
        float cnv[4];
        #pragma unroll
        for (int ni = 0; ni < 4; ++ni) cnv[ni] = cn_lds[wn*64 + ni*16 + c16];
        #pragma unroll
        for (int mi = 0; mi < 4; ++mi)
            #pragma unroll
            for (int ni = 0; ni < 4; ++ni)
                acc[mi][ni] = (fx4){cnv[ni], cnv[ni], cnv[ni], cnv[ni]};
    }

    // ---- main paired loop: tiles 0..61 ----
    #pragma unroll 1
    for (int Tp = 0; Tp < 31; ++Tp) {
        const int T = 2*Tp;
        // even tile (buf0): s0 stages (T+1,ks1,b1); s1 stages (T+2,ks0,b0)
        PH(0, 0, "vmcnt(6)", true, T + 1, 1, 1);
        PH(0, 1, "vmcnt(6)", true, T + 2, 0, 0);
        // odd tile (buf1): s0 stages (T+2,ks1,b0); s1 stages (T+3,ks0,b1)
        PH(1, 0, "vmcnt(6)", true, T + 2, 1, 0);
        PH(1, 1, "vmcnt(6)", true, T + 3, 0, 1);
        // keyed top-2 fold at nt boundary (tiles 7,15,...,55); registers only
        if ((Tp & 3) == 3) {
            const int nt = (2*Tp + 1) >> 3;   // 0..6
            #pragma unroll
            for (int ni = 0; ni < 4; ++ni) {
                const int idx5 = (nt << 2) | ni;
                #pragma unroll
                for (int mi = 0; mi < 4; ++mi)
                    #pragma unroll
                    for (int j = 0; j < 4; ++j) {
                        float key = __int_as_float(
                            (__float_as_int(acc[mi][ni][j]) & 0xFFFFFFE0) | idx5);
                        k1[mi][j] = __builtin_amdgcn_fmed3f(key, k0[mi][j], k1[mi][j]);
                        k0[mi][j] = fminf(k0[mi][j], key);
                    }
            }
            float cnv[4];
            #pragma unroll
            for (int ni = 0; ni < 4; ++ni)
                cnv[ni] = cn_lds[(nt + 1)*256 + wn*64 + ni*16 + c16];
            #pragma unroll
            for (int mi = 0; mi < 4; ++mi)
                #pragma unroll
                for (int ni = 0; ni < 4; ++ni)
                    acc[mi][ni] = (fx4){cnv[ni], cnv[ni], cnv[ni], cnv[ni]};
        }
    }
    // ---- tail: tile 62 (buf0), tile 63 (buf1) ----
    PH(0, 0, "vmcnt(6)", true, 63, 1, 1);    // phase 124: stage (63,ks1,b1)
    PH(0, 1, "vmcnt(6)", false, 0, 0, 0);    // phase 125
    PH(1, 0, "vmcnt(3)", false, 0, 0, 0);    // phase 126
    PH(1, 1, "vmcnt(0)", false, 0, 0, 0);    // phase 127
    // final fold (nt = 7)
    #pragma unroll
    for (int ni = 0; ni < 4; ++ni) {
        const int idx5 = (7 << 2) | ni;
        #pragma unroll
        for (int mi = 0; mi < 4; ++mi)
            #pragma unroll
            for (int j = 0; j < 4; ++j) {
                float key = __int_as_float(
                    (__float_as_int(acc[mi][ni][j]) & 0xFFFFFFE0) | idx5);
                k1[mi][j] = __builtin_amdgcn_fmed3f(key, k0[mi][j], k1[mi][j]);
                k0[mi][j] = fminf(k0[mi][j], key);
            }
    }
#undef STAGE_TO
#undef PH

    // ---------- epilogue (once per block) ----------
    float v0[4][4], v1[4][4]; int i0a[4][4];
    #pragma unroll
    for (int mi = 0; mi < 4; ++mi)
        #pragma unroll
        for (int j = 0; j < 4; ++j) {
            int b = __float_as_int(k0[mi][j]);
            int idx5 = b & 31;
            i0a[mi][j] = n0 + (idx5 >> 2)*256 + wn*64 + (idx5 & 3)*16 + c16;
            v0[mi][j]  = __int_as_float(b & 0xFFFFFFE0);
            v1[mi][j]  = __int_as_float(__float_as_int(k1[mi][j]) & 0xFFFFFFE0);
        }
    #pragma unroll
    for (int off = 1; off < 16; off <<= 1)
        #pragma unroll
        for (int mi = 0; mi < 4; ++mi)
            #pragma unroll
            for (int j = 0; j < 4; ++j) {
                float ov0 = __shfl_xor(v0[mi][j], off);
                int   oi0 = __shfl_xor(i0a[mi][j], off);
                float ov1 = __shfl_xor(v1[mi][j], off);
                float nv1 = fminf(fmaxf(v0[mi][j], ov0), fminf(v1[mi][j], ov1));
                bool take = (ov0 < v0[mi][j]) || (ov0 == v0[mi][j] && oi0 < i0a[mi][j]);
                v0[mi][j]  = take ? ov0 : v0[mi][j];
                i0a[mi][j] = take ? oi0 : i0a[mi][j];
                v1[mi][j]  = nv1;
            }

    // cross-wave (wn) merge through LDS (buf0 region; tail tiles were buf1)
    float* ev0 = (float*)smem;            // [128][4]
    int*   ei0 = (int*)(smem + 2048);
    float* ev1 = (float*)(smem + 4096);
    if (c16 == 0) {
        #pragma unroll
        for (int mi = 0; mi < 4; ++mi)
            #pragma unroll
            for (int j = 0; j < 4; ++j) {
                int r = wm*64 + mi*16 + q4*4 + j;
                ev0[r*4 + wn] = v0[mi][j];
                ei0[r*4 + wn] = i0a[mi][j];
                ev1[r*4 + wn] = v1[mi][j];
            }
    }
    __syncthreads();
    if (tid < 128) {
        float a0 = ev0[tid*4], a1 = ev1[tid*4]; int ai = ei0[tid*4];
        #pragma unroll
        for (int wc = 1; wc < 4; ++wc) {
            float b0 = ev0[tid*4 + wc], b1 = ev1[tid*4 + wc]; int bi = ei0[tid*4 + wc];
            float nv1 = fminf(fmaxf(a0, b0), fminf(a1, b1));
            bool take = (b0 < a0) || (b0 == a0 && bi < ai);
            a0 = take ? b0 : a0; ai = take ? bi : ai; a1 = nv1;
        }
        size_t o = (size_t)split * BT_N + m0 + tid;
        ws_v0[o] = a0; ws_i0[o] = ai; ws_v1[o] = a1;
    }
}

// ---------------- Kernel M: merge splits, flag close calls ----------------
__global__ __launch_bounds__(256) void vq_merge(
    const float* __restrict__ ws_v0, const int* __restrict__ ws_i0, const float* __restrict__ ws_v1,
    int* __restrict__ out_idx, int* __restrict__ list, unsigned int* __restrict__ counter)
{
    int q = blockIdx.x * 256 + threadIdx.x;
    float v0 = ws_v0[q]; int i0 = ws_i0[q]; float v1 = ws_v1[q];
    #pragma unroll
    for (int s = 1; s < NSPG; ++s) {
        size_t o = (size_t)s * BT_N + q;
        float sv0 = ws_v0[o]; int si0 = ws_i0[o]; float sv1 = ws_v1[o];
        v1 = fminf(fmaxf(v0, sv0), fminf(v1, sv1));
        bool take = (sv0 < v0) || (sv0 == v0 && si0 < i0);
        if (take) { v0 = sv0; i0 = si0; }
    }
    if (v1 - v0 < W_FLAG) {
        unsigned int pos = atomicAdd(counter, 1u);
        if (pos < CAP) { list[pos] = q; out_idx[q] = -1; }
        else           { out_idx[q] = i0; }       // graceful degradation (never hit)
    } else {
        out_idx[q] = i0;
    }
}

// ---------------- Kernel R: hi/lo fp16 MFMA rescan of flagged rows over all codes --
__global__ __launch_bounds__(256) void vq_rescan(
    const float* __restrict__ X,
    const _Float16* __restrict__ Ch, const _Float16* __restrict__ Cl,
    const float* __restrict__ cnormP,
    const int* __restrict__ list, const unsigned int* __restrict__ counter,
    float* __restrict__ rs_v0, int* __restrict__ rs_i0,
    float* __restrict__ rs_v1, int* __restrict__ rs_i1)
{
    int mcnt = min((int)*counter, CAP);
    const int m0 = blockIdx.x * 64;
    if (m0 >= mcnt) return;
    const int split = blockIdx.y;
    const int nbase = split * 512;

    __shared__ _Float16 Ah[64][72], Al[64][72];
    __shared__ _Float16 Bh[128][72], Bl[128][72];
    __shared__ int   qr[64];
    __shared__ float e_v0[64][4]; __shared__ int e_i0[64][4];
    __shared__ float e_v1[64][4]; __shared__ int e_i1[64][4];

    const int tid  = threadIdx.x;
    const int lane = tid & 63;
    const int w    = tid >> 6;
    const int c16  = lane & 15;
    const int q4   = lane >> 4;

    if (tid < 64) qr[tid] = list[min(m0 + tid, mcnt - 1)];
    __syncthreads();

    const int ar = tid >> 2;
    const int ac = (tid & 3) << 4;
    const size_t asrc_row = (size_t)qr[ar] * DDIM;

    float t2v0[4][4], t2v1[4][4]; int t2i0[4][4], t2i1[4][4];
    #pragma unroll
    for (int a = 0; a < 4; a++)
        #pragma unroll
        for (int b = 0; b < 4; b++) {
            t2v0[a][b] = 3e38f; t2v1[a][b] = 3e38f;
            t2i0[a][b] = 0x7fffffff; t2i1[a][b] = 0x7fffffff;
        }

    for (int nt = 0; nt < 4; ++nt) {
        const int nb = nbase + nt * 128;
        fx4 acc[4][2];
        #pragma unroll
        for (int mi = 0; mi < 4; ++mi)
            #pragma unroll
            for (int ni = 0; ni < 2; ++ni) acc[mi][ni] = (fx4){0.f, 0.f, 0.f, 0.f};

        for (int kb = 0; kb < DDIM; kb += 64) {
            {
                const float4* s4 = (const float4*)(X + asrc_row + kb + ac);
                float4 f0 = s4[0], f1 = s4[1], f2 = s4[2], f3 = s4[3];
                float fv[16] = {f0.x,f0.y,f0.z,f0.w, f1.x,f1.y,f1.z,f1.w,
                                f2.x,f2.y,f2.z,f2.w, f3.x,f3.y,f3.z,f3.w};
                half8 h0, l0, h1, l1;
                #pragma unroll
                for (int i = 0; i < 8; ++i) {
                    _Float16 hh = (_Float16)fv[i];
                    h0[i] = hh; l0[i] = (_Float16)(fv[i] - (float)hh);
                    _Float16 hh2 = (_Float16)fv[8+i];
                    h1[i] = hh2; l1[i] = (_Float16)(fv[8+i] - (float)hh2);
                }
                *(half8*)&Ah[ar][ac]     = h0;  *(half8*)&Ah[ar][ac + 8] = h1;
                *(half8*)&Al[ar][ac]     = l0;  *(half8*)&Al[ar][ac + 8] = l1;
            }
            #pragma unroll
            for (int g = 0; g < 4; ++g) {
                int li = g * 256 + tid;
                int br = li >> 3, bs = (li & 7) << 3;
                size_t src = (size_t)(nb + br) * DDIM + kb + bs;
                *(half8*)&Bh[br][bs] = *(const half8*)(Ch + src);
                *(half8*)&Bl[br][bs] = *(const half8*)(Cl + src);
            }
            __syncthreads();
            #pragma unroll
            for (int kk = 0; kk < 2; ++kk) {
                const int col = kk * 32 + q4 * 8;
                half8 ahf[4], alf[4], bhf[2], blf[2];
                #pragma unroll
                for (int mi = 0; mi < 4; ++mi) {
                    ahf[mi] = *(const half8*)&Ah[mi * 16 + c16][col];
                    alf[mi] = *(const half8*)&Al[mi * 16 + c16][col];
                }
                #pragma unroll
                for (int ni = 0; ni < 2; ++ni) {
                    int br = w * 32 + ni * 16 + c16;
                    bhf[ni] = *(const half8*)&Bh[br][col];
                    blf[ni] = *(const half8*)&Bl[br][col];
                }
                #pragma unroll
                for (int mi = 0; mi < 4; ++mi)
                    #pragma unroll
                    for (int ni = 0; ni < 2; ++ni) {
                        acc[mi][ni] = __builtin_amdgcn_mfma_f32_16x16x32_f16(ahf[mi], bhf[ni], acc[mi][ni], 0, 0, 0);
                        acc[mi][ni] = __builtin_amdgcn_mfma_f32_16x16x32_f16(ahf[mi], blf[ni], acc[mi][ni], 0, 0, 0);
                        acc[mi][ni] = __builtin_amdgcn_mfma_f32_16x16x32_f16(alf[mi], bhf[ni], acc[mi][ni], 0, 0, 0);
                    }
            }
            __syncthreads();
        }
        #pragma unroll
        for (int ni = 0; ni < 2; ++ni) {
            int code = nb + w * 32 + ni * 16 + c16;
            float cn = cnormP[code];
            #pragma unroll
            for (int mi = 0; mi < 4; ++mi)
                #pragma unroll
                for (int j = 0; j < 4; ++j)
                    t2_update(t2v0[mi][j], t2i0[mi][j], t2v1[mi][j], t2i1[mi][j],
                              acc[mi][ni][j] + cn, code);
        }
    }

    #pragma unroll
    for (int off = 1; off < 16; off <<= 1) {
        #pragma unroll
        for (int mi = 0; mi < 4; ++mi)
            #pragma unroll
            for (int j = 0; j < 4; ++j) {
                float ov0 = __shfl_xor(t2v0[mi][j], off);
                int   oi0 = __shfl_xor(t2i0[mi][j], off);
                float ov1 = __shfl_xor(t2v1[mi][j], off);
                int   oi1 = __shfl_xor(t2i1[mi][j], off);
                t2_merge(t2v0[mi][j], t2i0[mi][j], t2v1[mi][j], t2i1[mi][j],
                         ov0, oi0, ov1, oi1);
            }
    }
    if (c16 == 0) {
        #pragma unroll
        for (int mi = 0; mi < 4; ++mi)
            #pragma unroll
            for (int j = 0; j < 4; ++j) {
                int r = mi * 16 + q4 * 4 + j;
                e_v0[r][w] = t2v0[mi][j]; e_i0[r][w] = t2i0[mi][j];
                e_v1[r][w] = t2v1[mi][j]; e_i1[r][w] = t2i1[mi][j];
            }
    }
    __syncthreads();
    if (tid < 64 && m0 + tid < mcnt) {
        float v0 = e_v0[tid][0], v1 = e_v1[tid][0];
        int   i0 = e_i0[tid][0], i1 = e_i1[tid][0];
        #pragma unroll
        for (int wc = 1; wc < 4; ++wc)
            t2_merge(v0, i0, v1, i1, e_v0[tid][wc], e_i0[tid][wc], e_v1[tid][wc], e_i1[tid][wc]);
        size_t o = (size_t)split * CAP + m0 + tid;
        rs_v0[o] = v0; rs_i0[o] = i0; rs_v1[o] = v1; rs_i1[o] = i1;
    }
}

// ---------------- Kernel M2: merge rescan splits; wave-cooperative fp64 verdict --
__global__ __launch_bounds__(256) void vq_merge2(
    const float* __restrict__ X, const float* __restrict__ CB,
    const int* __restrict__ list, const unsigned int* __restrict__ counter,
    const float* __restrict__ rs_v0, const int* __restrict__ rs_i0,
    const float* __restrict__ rs_v1, const int* __restrict__ rs_i1,
    int* __restrict__ out_idx)
{
    int cnt = min((int)*counter, CAP);
    int m = blockIdx.x * 256 + threadIdx.x;
    const int lane = threadIdx.x & 63;
    bool active = m < cnt;
    int q = 0;
    float v0 = 3e38f, v1 = 3e38f; int i0 = 0x7fffffff, i1 = 0x7fffffff;
    if (active) {
        q = list[m];
        #pragma unroll
        for (int s = 0; s < NSPLIT; ++s) {
            size_t o = (size_t)s * CAP + m;
            t2_merge(v0, i0, v1, i1, rs_v0[o], rs_i0[o], rs_v1[o], rs_i1[o]);
        }
    }
    int pick = i0;
    unsigned long long need = __ballot(active && (v1 - v0 < W2));
    while (need) {
        int src = __ffsll((long long)need) - 1;
        need &= need - 1;
        int qq = __shfl(q, src), a = __shfl(i0, src), b = __shfl(i1, src);
        const float* xr  = X  + (size_t)qq * DDIM + lane * 8;
        const float* c0p = CB + (size_t)a  * DDIM + lane * 8;
        const float* c1p = CB + (size_t)b  * DDIM + lane * 8;
        double d0 = 0.0, d1 = 0.0;
        #pragma unroll
        for (int j = 0; j < 8; ++j) {
            double xv = (double)xr[j];
            double e0 = xv - (double)c0p[j]; d0 = fma(e0, e0, d0);
            double e1 = xv - (double)c1p[j]; d1 = fma(e1, e1, d1);
        }
        #pragma unroll
        for (int off = 1; off < 64; off <<= 1) {
            d0 += __shfl_xor(d0, off);
            d1 += __shfl_xor(d1, off);
        }
        if (lane == src) {
            bool tb = (d1 < d0) || (d1 == d0 && b < a);
            pick = tb ? b : a;
        }
    }
    if (active) out_idx[q] = pick;
}

// ---------------- Kernel G: gather codebook rows (wave per query) ----------------
__global__ __launch_bounds__(256) void vq_gather(
    const float* __restrict__ CB, const int* __restrict__ out_idx,
    float* __restrict__ out)
{
    const int wave = (blockIdx.x * 256 + threadIdx.x) >> 6;   // 0..4095
    const int lane = threadIdx.x & 63;
    for (int q = wave; q < BT_N; q += 4096) {
        int idx = out_idx[q];
        const float4* src = (const float4*)(CB + (size_t)idx * DDIM);
        float4* dst = (float4*)(out + (size_t)q * DDIM);
        dst[lane]      = src[lane];
        dst[lane + 64] = src[lane + 64];
    }
}

// ---------------- launcher ----------------
extern "C" void kernel_launch(void* const* d_in, const int* in_sizes, int n_in,
                              void* d_out, int out_size, void* d_ws, size_t ws_size,
                              hipStream_t stream) {
    const float* X  = (const float*)d_in[0];   // [32768,512]
    const float* CB = (const float*)d_in[1];   // [4096,512]
    float* out = (float*)d_out;

    char* ws = (char*)d_ws;
    _Float16* Xh       = (_Float16*)(ws + OFF_XH);
    _Float16* Ch       = (_Float16*)(ws + OFF_CH);
    _Float16* Cl       = (_Float16*)(ws + OFF_CL);
    float*    cnormP   = (float*)(ws + OFF_CNP);
    double*   cnorm_dp = (double*)(ws + OFF_CND);
    float*    ws_v0    = (float*)(ws + OFF_V0);
    int*      ws_i0    = (int*)(ws + OFF_I0);
    float*    ws_v1    = (float*)(ws + OFF_V1);
    int*      out_idx  = (int*)(ws + OFF_OIDX);
    int*      list     = (int*)(ws + OFF_LIST);
    unsigned int* counter = (unsigned int*)(ws + OFF_CNT);
    float*    rs_v0    = (float*)(ws + OFF_RSV0);
    int*      rs_i0    = (int*)(ws + OFF_RSI0);
    float*    rs_v1    = (float*)(ws + OFF_RSV1);
    int*      rs_i1    = (int*)(ws + OFF_RSI1);

    hipMemsetAsync(counter, 0, 4, stream);
    vq_cvt_x<<<2048, 256, 0, stream>>>(X, Xh, BT_N * DDIM / 8);
    vq_cvt_cb<<<KCB / 4, 256, 0, stream>>>(CB, Ch, Cl, cnormP, cnorm_dp);
    vq_gemm<<<512, 512, 0, stream>>>(Xh, Ch, cnormP, ws_v0, ws_i0, ws_v1);
    vq_merge<<<BT_N / 256, 256, 0, stream>>>(ws_v0, ws_i0, ws_v1, out_idx, list, counter);
    vq_rescan<<<dim3(CAP / 64, NSPLIT), 256, 0, stream>>>(X, Ch, Cl, cnormP, list, counter,
                                                          rs_v0, rs_i0, rs_v1, rs_i1);
    vq_merge2<<<CAP / 256, 256, 0, stream>>>(X, CB, list, counter,
                                             rs_v0, rs_i0, rs_v1, rs_i1, out_idx);
    vq_gather<<<1024, 256, 0, stream>>>(CB, out_idx, out);
}

// Round 6
// 444.162 us; speedup vs baseline: 1.5195x; 1.1060x over previous
//
#include <hip/hip_runtime.h>
#include <hip/hip_fp16.h>

// Problem constants
#define BT_N   32768   // B*T queries
#define DDIM   512
#define KCB    4096
#define W_FLAG 0.28f   // fp16-pass gap window (~18 sigma incl. key-quantization bias)
#define W2     0.01f   // refined-pass gap window (20x worst-case refined error)
#define CAP    8192    // max flagged queries handled (expected ~900)
#define NSPLIT 8       // rescan code splits (512 codes each)
#define NSPG   2       // gemm N-splits (4096 / 2048)

typedef _Float16 half8 __attribute__((ext_vector_type(8)));
typedef float    fx4   __attribute__((ext_vector_type(4)));

// ---------------- workspace layout ----------------
static constexpr size_t OFF_XH   = 0;                                // fp16 inputs          32 MB
static constexpr size_t OFF_CH   = OFF_XH   + (size_t)BT_N*DDIM*2;   // fp16 hi(-2c)          4 MB
static constexpr size_t OFF_CL   = OFF_CH   + (size_t)KCB*DDIM*2;    // fp16 lo(-2c)          4 MB
static constexpr size_t OFF_CNP  = OFF_CL   + (size_t)KCB*DDIM*2;    // float  cnorm+1024    16 KB
static constexpr size_t OFF_CND  = OFF_CNP  + (size_t)KCB*4;         // double cnorm         32 KB
static constexpr size_t OFF_V0   = OFF_CND  + (size_t)KCB*8;         // per (split,q) top1 val
static constexpr size_t OFF_I0   = OFF_V0   + (size_t)NSPG*BT_N*4;   // per (split,q) top1 idx
static constexpr size_t OFF_V1   = OFF_I0   + (size_t)NSPG*BT_N*4;   // per (split,q) 2nd val
static constexpr size_t OFF_OIDX = OFF_V1   + (size_t)NSPG*BT_N*4;   // final idx
static constexpr size_t OFF_LIST = OFF_OIDX + (size_t)BT_N*4;        // flagged query list
static constexpr size_t OFF_CNT  = OFF_LIST + (size_t)CAP*4;         // flagged counter
static constexpr size_t OFF_RSV0 = OFF_CNT  + 64;                    // rescan per-split top2
static constexpr size_t OFF_RSI0 = OFF_RSV0 + (size_t)NSPLIT*CAP*4;
static constexpr size_t OFF_RSV1 = OFF_RSI0 + (size_t)NSPLIT*CAP*4;
static constexpr size_t OFF_RSI1 = OFF_RSV1 + (size_t)NSPLIT*CAP*4;

// ---------------- async 16B global->LDS ----------------
__device__ __forceinline__ void async16(const void* g, void* l) {
    __builtin_amdgcn_global_load_lds(
        (const __attribute__((address_space(1))) unsigned int*)g,
        (__attribute__((address_space(3))) unsigned int*)l,
        16, 0, 0);
}

// ---------------- top-2 helpers (smaller-index tie-break, np.argmin semantics) ---
__device__ __forceinline__ void t2_update(float& v0, int& i0, float& v1, int& i1,
                                          float v, int idx) {
    bool t0 = (v < v0) || (v == v0 && idx < i0);
    bool t1 = (v < v1) || (v == v1 && idx < i1);
    float nv1 = t0 ? v0 : (t1 ? v : v1);
    int   ni1 = t0 ? i0 : (t1 ? idx : i1);
    v1 = nv1; i1 = ni1;
    v0 = t0 ? v : v0;
    i0 = t0 ? idx : i0;
}
__device__ __forceinline__ void t2_merge(float& v0, int& i0, float& v1, int& i1,
                                         float ov0, int oi0, float ov1, int oi1) {
    bool oa = (ov0 < v0) || (ov0 == v0 && oi0 < i0);
    float w0 = oa ? ov0 : v0;  int wi0 = oa ? oi0 : i0;
    float l0 = oa ? v0 : ov0;  int li0 = oa ? i0 : oi0;
    float ws = oa ? ov1 : v1;  int wsi = oa ? oi1 : i1;
    bool sb = (l0 < ws) || (l0 == ws && li0 < wsi);
    v0 = w0; i0 = wi0;
    v1 = sb ? l0 : ws; i1 = sb ? li0 : wsi;
}

// ---------------- K_x: convert inputs fp32 -> fp16 ----------------
__global__ __launch_bounds__(256) void vq_cvt_x(const float* __restrict__ X,
                                                _Float16* __restrict__ Xh, int n8) {
    int i = blockIdx.x * 256 + threadIdx.x;
    int stride = gridDim.x * 256;
    for (; i < n8; i += stride) {
        float4 a = ((const float4*)X)[(size_t)i*2];
        float4 b = ((const float4*)X)[(size_t)i*2 + 1];
        half8 h;
        h[0]=(_Float16)a.x; h[1]=(_Float16)a.y; h[2]=(_Float16)a.z; h[3]=(_Float16)a.w;
        h[4]=(_Float16)b.x; h[5]=(_Float16)b.y; h[6]=(_Float16)b.z; h[7]=(_Float16)b.w;
        ((half8*)Xh)[i] = h;
    }
}

// ---------------- K_cb: codebook -> fp16 hi/lo of (-2c), cnorms (4 rows/block) ---
__global__ __launch_bounds__(256) void vq_cvt_cb(const float* __restrict__ CB,
                                                 _Float16* __restrict__ Ch,
                                                 _Float16* __restrict__ Cl,
                                                 float* __restrict__ cnormP,
                                                 double* __restrict__ cnorm_dp) {
    int r = blockIdx.x * 4 + (threadIdx.x >> 6);
    int t = threadIdx.x & 63;
    const float* row = CB + (size_t)r * DDIM;
    float4 a = ((const float4*)row)[t*2];
    float4 b = ((const float4*)row)[t*2 + 1];
    double s = (double)a.x*a.x + (double)a.y*a.y + (double)a.z*a.z + (double)a.w*a.w
             + (double)b.x*b.x + (double)b.y*b.y + (double)b.z*b.z + (double)b.w*b.w;
    float f[8] = {-2.0f*a.x, -2.0f*a.y, -2.0f*a.z, -2.0f*a.w,
                  -2.0f*b.x, -2.0f*b.y, -2.0f*b.z, -2.0f*b.w};
    half8 h, l;
    #pragma unroll
    for (int i = 0; i < 8; ++i) {
        _Float16 hh = (_Float16)f[i];
        h[i] = hh;
        l[i] = (_Float16)(f[i] - (float)hh);
    }
    ((half8*)(Ch + (size_t)r * DDIM))[t] = h;
    ((half8*)(Cl + (size_t)r * DDIM))[t] = l;
    #pragma unroll
    for (int off = 1; off < 64; off <<= 1) s += __shfl_xor(s, off);
    if (t == 0) { cnorm_dp[r] = s; cnormP[r] = (float)(s + 1024.0); }
}

// ---------------- Kernel A: 256x256 m201-cadence GEMM, nt-continuous + keyed top-2
// 8 waves (2M x 4N), wave owns 128x64 -> acc[8][4] (128 AGPR) + keys k0/k1[8][4]
// (64 VGPR); ~125 VGPR + 128 AGPR under the 256 budget of 1 block/CU (LDS 139KB).
// Per block: 256 queries x 2048 codes (split), 64 CONTINUOUS K-tiles (g=nt*8+kt),
// 4 phases each (P1:ks0/mi0-3, P2:ks0/mi4-7, P3:ks1/mi0-3, P4:ks1/mi4-7).
// m201 phase: {ds_read frags (8 or 4); stage 1 half-tile (2 issues); barrier;
// lgkmcnt(0); sched_barrier; setprio(1); 16 MFMA; setprio(0); barrier} — reads
// and stage issue BEFORE the first barrier (latency overlaps sync; the 2nd
// barrier of the previous phase makes it race-free). vmcnt(6) ONCE per K-tile
// (end of P4); never 0 until the final drain. Stage targets: P1=(A,ks1)g+1
// ->buf^1 (last read g-1.P4); P2/P3/P4=(B,ks0)/(A,ks0)/(B,ks1) of g+2 ->buf
// (last read P1/P2/P3). Prologue stages 7 half-tiles; end-of-tile vmcnt(6)
// retires exactly the next tile's 4 regions (8 loads of 14 outstanding).
// LDS subtiled [group16][q4][row15]: wave ds_read_b128 = 1KB contiguous
// (conflict-free); gload_lds dest linear = tid*16, source carries permutation.
// Per CU per K-tile: MFMA 2480 cyc vs ds_read 2304 cyc -> compute-bound (r4's
// 64x64 wave tile was LDS-read-bound: 768 > 620 cyc/phase, the 26% cause).
// Keys: score = cnorm+1024-2x.c > 0; low 5 mantissa bits carry (nt<<2)|ni
// (monotone in code index; quantization ~8e-3 << W_FLAG). Same as 474us base.
__device__ __forceinline__ void stage_ht(char* smem, int tid,
    const _Float16* __restrict__ srcA, const _Float16* __restrict__ srcB,
    int mat, int ts, int ks, int bd)
{
    char* d = smem + bd*65536 + mat*32768 + ks*16384 + tid*16;
    const _Float16* s = mat ? (srcB + (size_t)(ts >> 3) * (256*DDIM)) : srcA;
    s += (ts & 7)*64 + ks*32;
    async16(s, d);
    async16(s + (size_t)128*DDIM, d + 8192);
}

template<int BUF, int VM, bool S1, bool S234>
__device__ __forceinline__ void do_tile(int g, char* smem, int tid,
    const _Float16* __restrict__ srcA, const _Float16* __restrict__ srcB,
    int aoff, int boff, fx4 (&acc)[8][4])
{
    const char* ab = smem + BUF*65536 + aoff;
    const char* bb = smem + BUF*65536 + boff;
    half8 af[4], bf[4];

#define MFMA4x4(MB)                                                            \
    _Pragma("unroll")                                                          \
    for (int mi = 0; mi < 4; ++mi)                                             \
        _Pragma("unroll")                                                      \
        for (int ni = 0; ni < 4; ++ni)                                         \
            acc[(MB)+mi][ni] = __builtin_amdgcn_mfma_f32_16x16x32_f16(af[mi], bf[ni], acc[(MB)+mi][ni], 0, 0, 0)

    // ---- P1: ks0, mi 0..3 (8 reads) ----
    #pragma unroll
    for (int ni = 0; ni < 4; ++ni) bf[ni] = *(const half8*)(bb + ni*1024);
    #pragma unroll
    for (int mi = 0; mi < 4; ++mi) af[mi] = *(const half8*)(ab + mi*1024);
    if (S1) stage_ht(smem, tid, srcA, srcB, 0, g + 1, 1, BUF ^ 1);
    __builtin_amdgcn_s_barrier();
    asm volatile("s_waitcnt lgkmcnt(0)" ::: "memory");
    __builtin_amdgcn_sched_barrier(0);
    __builtin_amdgcn_s_setprio(1);
    MFMA4x4(0);
    __builtin_amdgcn_s_setprio(0);
    __builtin_amdgcn_s_barrier();

    // ---- P2: ks0, mi 4..7 (4 reads) ----
    #pragma unroll
    for (int mi = 0; mi < 4; ++mi) af[mi] = *(const half8*)(ab + (4 + mi)*1024);
    if (S234) stage_ht(smem, tid, srcA, srcB, 1, g + 2, 0, BUF);
    __builtin_amdgcn_s_barrier();
    asm volatile("s_waitcnt lgkmcnt(0)" ::: "memory");
    __builtin_amdgcn_sched_barrier(0);
    __builtin_amdgcn_s_setprio(1);
    MFMA4x4(4);
    __builtin_amdgcn_s_setprio(0);
    __builtin_amdgcn_s_barrier();

    // ---- P3: ks1, mi 0..3 (8 reads) ----
    #pragma unroll
    for (int ni = 0; ni < 4; ++ni) bf[ni] = *(const half8*)(bb + 16384 + ni*1024);
    #pragma unroll
    for (int mi = 0; mi < 4; ++mi) af[mi] = *(const half8*)(ab + 16384 + mi*1024);
    if (S234) stage_ht(smem, tid, srcA, srcB, 0, g + 2, 0, BUF);
    __builtin_amdgcn_s_barrier();
    asm volatile("s_waitcnt lgkmcnt(0)" ::: "memory");
    __builtin_amdgcn_sched_barrier(0);
    __builtin_amdgcn_s_setprio(1);
    MFMA4x4(0);
    __builtin_amdgcn_s_setprio(0);
    __builtin_amdgcn_s_barrier();

    // ---- P4: ks1, mi 4..7 (4 reads) + K-tile-boundary vmcnt ----
    #pragma unroll
    for (int mi = 0; mi < 4; ++mi) af[mi] = *(const half8*)(ab + 16384 + (4 + mi)*1024);
    if (S234) stage_ht(smem, tid, srcA, srcB, 1, g + 2, 1, BUF);
    __builtin_amdgcn_s_barrier();
    asm volatile("s_waitcnt lgkmcnt(0)" ::: "memory");
    __builtin_amdgcn_sched_barrier(0);
    __builtin_amdgcn_s_setprio(1);
    MFMA4x4(4);
    __builtin_amdgcn_s_setprio(0);
    if (VM == 6)      asm volatile("s_waitcnt vmcnt(6)" ::: "memory");
    else if (VM == 0) asm volatile("s_waitcnt vmcnt(0)" ::: "memory");
    __builtin_amdgcn_s_barrier();
#undef MFMA4x4
}

__global__ __launch_bounds__(512, 2) void vq_gemm(
    const _Float16* __restrict__ Xh, const _Float16* __restrict__ Ch,
    const float* __restrict__ cnormP,
    float* __restrict__ ws_v0, int* __restrict__ ws_i0, float* __restrict__ ws_v1)
{
    __shared__ ulonglong2 smem_u[139264/16];   // 2buf x (A 32KB + B 32KB) + 8KB cn
    char* smem = (char*)smem_u;
    float* cn_lds = (float*)(smem + 131072);

    const int tid  = threadIdx.x;
    const int wid  = tid >> 6;
    const int lane = tid & 63;
    const int c16  = lane & 15;
    const int q4   = lane >> 4;
    const int wm   = wid >> 2;      // 0..1  (M half: rows wm*128..+127)
    const int wn   = wid & 3;       // 0..3  (N quarter: rows wn*64..+63)

    // XCD-aware job map: XCD x owns one split (its 2MB B panel stays L2-hot)
    const int bid   = blockIdx.x;
    const int x     = bid & 7;
    const int split = x & 1;
    const int mblk  = (x >> 1) * 32 + (bid >> 3);
    const int m0    = mblk * 256;
    const int n0    = split * 2048;

    // staging source: thread t covers (row (t>>6)*16+(t&15), colchunk (t>>4)&3)
    const int srow = ((tid >> 6) << 4) | (tid & 15);
    const int scol = ((tid >> 4) & 3) << 3;
    const _Float16* srcA = Xh + (size_t)(m0 + srow) * DDIM + scol;
    const _Float16* srcB = Ch + (size_t)(n0 + srow) * DDIM + scol;

    // frag-read offsets: elem (row,chunk q) at group*1024 + q*256 + (row&15)*16
    const int aoff = wm*8192 + q4*256 + c16*16;           // A group = wm*8 + mi
    const int boff = 32768 + wn*4096 + q4*256 + c16*16;   // B group = wn*4 + ni

    // ---- prologue: cnorm stash, drained before the counted stream starts ----
    float4 cnld = ((const float4*)(cnormP + n0))[tid];   // 512 x 16B = 8KB
    asm volatile("s_waitcnt vmcnt(0)" ::: "memory");
    ((float4*)cn_lds)[tid] = cnld;

    // stage 7 half-tiles: tile0 complete + tile1 minus (A,ks1)
    stage_ht(smem, tid, srcA, srcB, 1, 0, 0, 0);   // (B,ks0) 0
    stage_ht(smem, tid, srcA, srcB, 0, 0, 0, 0);   // (A,ks0) 0
    stage_ht(smem, tid, srcA, srcB, 1, 0, 1, 0);   // (B,ks1) 0
    stage_ht(smem, tid, srcA, srcB, 0, 0, 1, 0);   // (A,ks1) 0
    stage_ht(smem, tid, srcA, srcB, 1, 1, 0, 1);   // (B,ks0) 1
    stage_ht(smem, tid, srcA, srcB, 0, 1, 0, 1);   // (A,ks0) 1
    stage_ht(smem, tid, srcA, srcB, 1, 1, 1, 1);   // (B,ks1) 1

    asm volatile("s_waitcnt lgkmcnt(0)" ::: "memory");   // cn ds_write done
    __builtin_amdgcn_s_barrier();                        // cn stash visible

    float k0[8][4], k1[8][4];
    #pragma unroll
    for (int mi = 0; mi < 8; ++mi)
        #pragma unroll
        for (int j = 0; j < 4; ++j) { k0[mi][j] = 3e38f; k1[mi][j] = 3e38f; }

    fx4 acc[8][4];
    {
        float cnv[4];
        #pragma unroll
        for (int ni = 0; ni < 4; ++ni) cnv[ni] = cn_lds[wn*64 + ni*16 + c16];
        #pragma unroll
        for (int mi = 0; mi < 8; ++mi)
            #pragma unroll
            for (int ni = 0; ni < 4; ++ni)
                acc[mi][ni] = (fx4){cnv[ni], cnv[ni], cnv[ni], cnv[ni]};
    }

    asm volatile("s_waitcnt vmcnt(6)" ::: "memory");     // tile 0 resident
    __builtin_amdgcn_s_barrier();

#define FOLDNT(NT) do {                                                         \
    _Pragma("unroll")                                                           \
    for (int ni = 0; ni < 4; ++ni) {                                            \
        const int idx5 = ((NT) << 2) | ni;                                      \
        _Pragma("unroll")                                                       \
        for (int mi = 0; mi < 8; ++mi)                                          \
            _Pragma("unroll")                                                   \
            for (int j = 0; j < 4; ++j) {                                       \
                float key = __int_as_float(                                     \
                    (__float_as_int(acc[mi][ni][j]) & 0xFFFFFFE0) | idx5);      \
                k1[mi][j] = __builtin_amdgcn_fmed3f(key, k0[mi][j], k1[mi][j]); \
                k0[mi][j] = fminf(k0[mi][j], key);                              \
            }                                                                   \
    }                                                                           \
} while (0)

    // ---- main loop: tile pairs 0..30 (tiles 0..61) ----
    #pragma unroll 1
    for (int p = 0; p < 31; ++p) {
        do_tile<0, 6, true, true>(2*p,     smem, tid, srcA, srcB, aoff, boff, acc);
        do_tile<1, 6, true, true>(2*p + 1, smem, tid, srcA, srcB, aoff, boff, acc);
        if ((p & 3) == 3) {                 // nt boundary (tiles 7,15,...,55)
            const int nt = (2*p + 1) >> 3;  // 0..6
            FOLDNT(nt);
            float cnv[4];
            #pragma unroll
            for (int ni = 0; ni < 4; ++ni)
                cnv[ni] = cn_lds[(nt + 1)*256 + wn*64 + ni*16 + c16];
            #pragma unroll
            for (int mi = 0; mi < 8; ++mi)
                #pragma unroll
                for (int ni = 0; ni < 4; ++ni)
                    acc[mi][ni] = (fx4){cnv[ni], cnv[ni], cnv[ni], cnv[ni]};
        }
    }
    // ---- tail: tile 62 (stages only (A,ks1)63; final drain), tile 63 ----
    do_tile<0, 0, true,  false>(62, smem, tid, srcA, srcB, aoff, boff, acc);
    do_tile<1, 2, false, false>(63, smem, tid, srcA, srcB, aoff, boff, acc);
    FOLDNT(7);
#undef FOLDNT

    // ---------- epilogue (once per block) ----------
    float v0[8][4], v1[8][4]; int i0a[8][4];
    #pragma unroll
    for (int mi = 0; mi < 8; ++mi)
        #pragma unroll
        for (int j = 0; j < 4; ++j) {
            int b = __float_as_int(k0[mi][j]);
            int idx5 = b & 31;
            i0a[mi][j] = n0 + (idx5 >> 2)*256 + wn*64 + (idx5 & 3)*16 + c16;
            v0[mi][j]  = __int_as_float(b & 0xFFFFFFE0);
            v1[mi][j]  = __int_as_float(__float_as_int(k1[mi][j]) & 0xFFFFFFE0);
        }
    #pragma unroll
    for (int off = 1; off < 16; off <<= 1)
        #pragma unroll
        for (int mi = 0; mi < 8; ++mi)
            #pragma unroll
            for (int j = 0; j < 4; ++j) {
                float ov0 = __shfl_xor(v0[mi][j], off);
                int   oi0 = __shfl_xor(i0a[mi][j], off);
                float ov1 = __shfl_xor(v1[mi][j], off);
                float nv1 = fminf(fmaxf(v0[mi][j], ov0), fminf(v1[mi][j], ov1));
                bool take = (ov0 < v0[mi][j]) || (ov0 == v0[mi][j] && oi0 < i0a[mi][j]);
                v0[mi][j]  = take ? ov0 : v0[mi][j];
                i0a[mi][j] = take ? oi0 : i0a[mi][j];
                v1[mi][j]  = nv1;
            }

    // cross-wave (wn) merge through LDS (buf0 bytes 0..12KB; tile 63 was buf1)
    float* ev0 = (float*)smem;            // [256][4]
    int*   ei0 = (int*)(smem + 4096);
    float* ev1 = (float*)(smem + 8192);
    if (c16 == 0) {
        #pragma unroll
        for (int mi = 0; mi < 8; ++mi)
            #pragma unroll
            for (int j = 0; j < 4; ++j) {
                int r = wm*128 + mi*16 + q4*4 + j;
                ev0[r*4 + wn] = v0[mi][j];
                ei0[r*4 + wn] = i0a[mi][j];
                ev1[r*4 + wn] = v1[mi][j];
            }
    }
    __syncthreads();
    if (tid < 256) {
        float a0 = ev0[tid*4], a1 = ev1[tid*4]; int ai = ei0[tid*4];
        #pragma unroll
        for (int wc = 1; wc < 4; ++wc) {
            float b0 = ev0[tid*4 + wc], b1 = ev1[tid*4 + wc]; int bi = ei0[tid*4 + wc];
            float nv1 = fminf(fmaxf(a0, b0), fminf(a1, b1));
            bool take = (b0 < a0) || (b0 == a0 && bi < ai);
            a0 = take ? b0 : a0; ai = take ? bi : ai; a1 = nv1;
        }
        size_t o = (size_t)split * BT_N + m0 + tid;
        ws_v0[o] = a0; ws_i0[o] = ai; ws_v1[o] = a1;
    }
}

// ---------------- Kernel M: merge splits, flag close calls ----------------
__global__ __launch_bounds__(256) void vq_merge(
    const float* __restrict__ ws_v0, const int* __restrict__ ws_i0, const float* __restrict__ ws_v1,
    int* __restrict__ out_idx, int* __restrict__ list, unsigned int* __restrict__ counter)
{
    int q = blockIdx.x * 256 + threadIdx.x;
    float v0 = ws_v0[q]; int i0 = ws_i0[q]; float v1 = ws_v1[q];
    #pragma unroll
    for (int s = 1; s < NSPG; ++s) {
        size_t o = (size_t)s * BT_N + q;
        float sv0 = ws_v0[o]; int si0 = ws_i0[o]; float sv1 = ws_v1[o];
        v1 = fminf(fmaxf(v0, sv0), fminf(v1, sv1));
        bool take = (sv0 < v0) || (sv0 == v0 && si0 < i0);
        if (take) { v0 = sv0; i0 = si0; }
    }
    if (v1 - v0 < W_FLAG) {
        unsigned int pos = atomicAdd(counter, 1u);
        if (pos < CAP) { list[pos] = q; out_idx[q] = -1; }
        else           { out_idx[q] = i0; }       // graceful degradation (never hit)
    } else {
        out_idx[q] = i0;
    }
}

// ---------------- Kernel R: hi/lo fp16 MFMA rescan of flagged rows over all codes --
__global__ __launch_bounds__(256) void vq_rescan(
    const float* __restrict__ X,
    const _Float16* __restrict__ Ch, const _Float16* __restrict__ Cl,
    const float* __restrict__ cnormP,
    const int* __restrict__ list, const unsigned int* __restrict__ counter,
    float* __restrict__ rs_v0, int* __restrict__ rs_i0,
    float* __restrict__ rs_v1, int* __restrict__ rs_i1)
{
    int mcnt = min((int)*counter, CAP);
    const int m0 = blockIdx.x * 64;
    if (m0 >= mcnt) return;
    const int split = blockIdx.y;
    const int nbase = split * 512;

    __shared__ _Float16 Ah[64][72], Al[64][72];
    __shared__ _Float16 Bh[128][72], Bl[128][72];
    __shared__ int   qr[64];
    __shared__ float e_v0[64][4]; __shared__ int e_i0[64][4];
    __shared__ float e_v1[64][4]; __shared__ int e_i1[64][4];

    const int tid  = threadIdx.x;
    const int lane = tid & 63;
    const int w    = tid >> 6;
    const int c16  = lane & 15;
    const int q4   = lane >> 4;

    if (tid < 64) qr[tid] = list[min(m0 + tid, mcnt - 1)];
    __syncthreads();

    const int ar = tid >> 2;
    const int ac = (tid & 3) << 4;
    const size_t asrc_row = (size_t)qr[ar] * DDIM;

    float t2v0[4][4], t2v1[4][4]; int t2i0[4][4], t2i1[4][4];
    #pragma unroll
    for (int a = 0; a < 4; a++)
        #pragma unroll
        for (int b = 0; b < 4; b++) {
            t2v0[a][b] = 3e38f; t2v1[a][b] = 3e38f;
            t2i0[a][b] = 0x7fffffff; t2i1[a][b] = 0x7fffffff;
        }

    for (int nt = 0; nt < 4; ++nt) {
        const int nb = nbase + nt * 128;
        fx4 acc[4][2];
        #pragma unroll
        for (int mi = 0; mi < 4; ++mi)
            #pragma unroll
            for (int ni = 0; ni < 2; ++ni) acc[mi][ni] = (fx4){0.f, 0.f, 0.f, 0.f};

        for (int kb = 0; kb < DDIM; kb += 64) {
            {
                const float4* s4 = (const float4*)(X + asrc_row + kb + ac);
                float4 f0 = s4[0], f1 = s4[1], f2 = s4[2], f3 = s4[3];
                float fv[16] = {f0.x,f0.y,f0.z,f0.w, f1.x,f1.y,f1.z,f1.w,
                                f2.x,f2.y,f2.z,f2.w, f3.x,f3.y,f3.z,f3.w};
                half8 h0, l0, h1, l1;
                #pragma unroll
                for (int i = 0; i < 8; ++i) {
                    _Float16 hh = (_Float16)fv[i];
                    h0[i] = hh; l0[i] = (_Float16)(fv[i] - (float)hh);
                    _Float16 hh2 = (_Float16)fv[8+i];
                    h1[i] = hh2; l1[i] = (_Float16)(fv[8+i] - (float)hh2);
                }
                *(half8*)&Ah[ar][ac]     = h0;  *(half8*)&Ah[ar][ac + 8] = h1;
                *(half8*)&Al[ar][ac]     = l0;  *(half8*)&Al[ar][ac + 8] = l1;
            }
            #pragma unroll
            for (int g = 0; g < 4; ++g) {
                int li = g * 256 + tid;
                int br = li >> 3, bs = (li & 7) << 3;
                size_t src = (size_t)(nb + br) * DDIM + kb + bs;
                *(half8*)&Bh[br][bs] = *(const half8*)(Ch + src);
                *(half8*)&Bl[br][bs] = *(const half8*)(Cl + src);
            }
            __syncthreads();
            #pragma unroll
            for (int kk = 0; kk < 2; ++kk) {
                const int col = kk * 32 + q4 * 8;
                half8 ahf[4], alf[4], bhf[2], blf[2];
                #pragma unroll
                for (int mi = 0; mi < 4; ++mi) {
                    ahf[mi] = *(const half8*)&Ah[mi * 16 + c16][col];
                    alf[mi] = *(const half8*)&Al[mi * 16 + c16][col];
                }
                #pragma unroll
                for (int ni = 0; ni < 2; ++ni) {
                    int br = w * 32 + ni * 16 + c16;
                    bhf[ni] = *(const half8*)&Bh[br][col];
                    blf[ni] = *(const half8*)&Bl[br][col];
                }
                #pragma unroll
                for (int mi = 0; mi < 4; ++mi)
                    #pragma unroll
                    for (int ni = 0; ni < 2; ++ni) {
                        acc[mi][ni] = __builtin_amdgcn_mfma_f32_16x16x32_f16(ahf[mi], bhf[ni], acc[mi][ni], 0, 0, 0);
                        acc[mi][ni] = __builtin_amdgcn_mfma_f32_16x16x32_f16(ahf[mi], blf[ni], acc[mi][ni], 0, 0, 0);
                        acc[mi][ni] = __builtin_amdgcn_mfma_f32_16x16x32_f16(alf[mi], bhf[ni], acc[mi][ni], 0, 0, 0);
                    }
            }
            __syncthreads();
        }
        #pragma unroll
        for (int ni = 0; ni < 2; ++ni) {
            int code = nb + w * 32 + ni * 16 + c16;
            float cn = cnormP[code];
            #pragma unroll
            for (int mi = 0; mi < 4; ++mi)
                #pragma unroll
                for (int j = 0; j < 4; ++j)
                    t2_update(t2v0[mi][j], t2i0[mi][j], t2v1[mi][j], t2i1[mi][j],
                              acc[mi][ni][j] + cn, code);
        }
    }

    #pragma unroll
    for (int off = 1; off < 16; off <<= 1) {
        #pragma unroll
        for (int mi = 0; mi < 4; ++mi)
            #pragma unroll
            for (int j = 0; j < 4; ++j) {
                float ov0 = __shfl_xor(t2v0[mi][j], off);
                int   oi0 = __shfl_xor(t2i0[mi][j], off);
                float ov1 = __shfl_xor(t2v1[mi][j], off);
                int   oi1 = __shfl_xor(t2i1[mi][j], off);
                t2_merge(t2v0[mi][j], t2i0[mi][j], t2v1[mi][j], t2i1[mi][j],
                         ov0, oi0, ov1, oi1);
            }
    }
    if (c16 == 0) {
        #pragma unroll
        for (int mi = 0; mi < 4; ++mi)
            #pragma unroll
            for (int j = 0; j < 4; ++j) {
                int r = mi * 16 + q4 * 4 + j;
                e_v0[r][w] = t2v0[mi][j]; e_i0[r][w] = t2i0[mi][j];
                e_v1[r][w] = t2v1[mi][j]; e_i1[r][w] = t2i1[mi][j];
            }
    }
    __syncthreads();
    if (tid < 64 && m0 + tid < mcnt) {
        float v0 = e_v0[tid][0], v1 = e_v1[tid][0];
        int   i0 = e_i0[tid][0], i1 = e_i1[tid][0];
        #pragma unroll
        for (int wc = 1; wc < 4; ++wc)
            t2_merge(v0, i0, v1, i1, e_v0[tid][wc], e_i0[tid][wc], e_v1[tid][wc], e_i1[tid][wc]);
        size_t o = (size_t)split * CAP + m0 + tid;
        rs_v0[o] = v0; rs_i0[o] = i0; rs_v1[o] = v1; rs_i1[o] = i1;
    }
}

// ---------------- Kernel M2: merge rescan splits; wave-cooperative fp64 verdict --
__global__ __launch_bounds__(256) void vq_merge2(
    const float* __restrict__ X, const float* __restrict__ CB,
    const int* __restrict__ list, const unsigned int* __restrict__ counter,
    const float* __restrict__ rs_v0, const int* __restrict__ rs_i0,
    const float* __restrict__ rs_v1, const int* __restrict__ rs_i1,
    int* __restrict__ out_idx)
{
    int cnt = min((int)*counter, CAP);
    int m = blockIdx.x * 256 + threadIdx.x;
    const int lane = threadIdx.x & 63;
    bool active = m < cnt;
    int q = 0;
    float v0 = 3e38f, v1 = 3e38f; int i0 = 0x7fffffff, i1 = 0x7fffffff;
    if (active) {
        q = list[m];
        #pragma unroll
        for (int s = 0; s < NSPLIT; ++s) {
            size_t o = (size_t)s * CAP + m;
            t2_merge(v0, i0, v1, i1, rs_v0[o], rs_i0[o], rs_v1[o], rs_i1[o]);
        }
    }
    int pick = i0;
    unsigned long long need = __ballot(active && (v1 - v0 < W2));
    while (need) {
        int src = __ffsll((long long)need) - 1;
        need &= need - 1;
        int qq = __shfl(q, src), a = __shfl(i0, src), b = __shfl(i1, src);
        const float* xr  = X  + (size_t)qq * DDIM + lane * 8;
        const float* c0p = CB + (size_t)a  * DDIM + lane * 8;
        const float* c1p = CB + (size_t)b  * DDIM + lane * 8;
        double d0 = 0.0, d1 = 0.0;
        #pragma unroll
        for (int j = 0; j < 8; ++j) {
            double xv = (double)xr[j];
            double e0 = xv - (double)c0p[j]; d0 = fma(e0, e0, d0);
            double e1 = xv - (double)c1p[j]; d1 = fma(e1, e1, d1);
        }
        #pragma unroll
        for (int off = 1; off < 64; off <<= 1) {
            d0 += __shfl_xor(d0, off);
            d1 += __shfl_xor(d1, off);
        }
        if (lane == src) {
            bool tb = (d1 < d0) || (d1 == d0 && b < a);
            pick = tb ? b : a;
        }
    }
    if (active) out_idx[q] = pick;
}

// ---------------- Kernel G: gather codebook rows (wave per query) ----------------
__global__ __launch_bounds__(256) void vq_gather(
    const float* __restrict__ CB, const int* __restrict__ out_idx,
    float* __restrict__ out)
{
    const int wave = (blockIdx.x * 256 + threadIdx.x) >> 6;   // 0..4095
    const int lane = threadIdx.x & 63;
    for (int q = wave; q < BT_N; q += 4096) {
        int idx = out_idx[q];
        const float4* src = (const float4*)(CB + (size_t)idx * DDIM);
        float4* dst = (float4*)(out + (size_t)q * DDIM);
        dst[lane]      = src[lane];
        dst[lane + 64] = src[lane + 64];
    }
}

// ---------------- launcher ----------------
extern "C" void kernel_launch(void* const* d_in, const int* in_sizes, int n_in,
                              void* d_out, int out_size, void* d_ws, size_t ws_size,
                              hipStream_t stream) {
    const float* X  = (const float*)d_in[0];   // [32768,512]
    const float* CB = (const float*)d_in[1];   // [4096,512]
    float* out = (float*)d_out;

    char* ws = (char*)d_ws;
    _Float16* Xh       = (_Float16*)(ws + OFF_XH);
    _Float16* Ch       = (_Float16*)(ws + OFF_CH);
    _Float16* Cl       = (_Float16*)(ws + OFF_CL);
    float*    cnormP   = (float*)(ws + OFF_CNP);
    double*   cnorm_dp = (double*)(ws + OFF_CND);
    float*    ws_v0    = (float*)(ws + OFF_V0);
    int*      ws_i0    = (int*)(ws + OFF_I0);
    float*    ws_v1    = (float*)(ws + OFF_V1);
    int*      out_idx  = (int*)(ws + OFF_OIDX);
    int*      list     = (int*)(ws + OFF_LIST);
    unsigned int* counter = (unsigned int*)(ws + OFF_CNT);
    float*    rs_v0    = (float*)(ws + OFF_RSV0);
    int*      rs_i0    = (int*)(ws + OFF_RSI0);
    float*    rs_v1    = (float*)(ws + OFF_RSV1);
    int*      rs_i1    = (int*)(ws + OFF_RSI1);

    hipMemsetAsync(counter, 0, 4, stream);
    vq_cvt_x<<<2048, 256, 0, stream>>>(X, Xh, BT_N * DDIM / 8);
    vq_cvt_cb<<<KCB / 4, 256, 0, stream>>>(CB, Ch, Cl, cnormP, cnorm_dp);
    vq_gemm<<<256, 512, 0, stream>>>(Xh, Ch, cnormP, ws_v0, ws_i0, ws_v1);
    vq_merge<<<BT_N / 256, 256, 0, stream>>>(ws_v0, ws_i0, ws_v1, out_idx, list, counter);
    vq_rescan<<<dim3(CAP / 64, NSPLIT), 256, 0, stream>>>(X, Ch, Cl, cnormP, list, counter,
                                                          rs_v0, rs_i0, rs_v1, rs_i1);
    vq_merge2<<<CAP / 256, 256, 0, stream>>>(X, CB, list, counter,
                                             rs_v0, rs_i0, rs_v1, rs_i1, out_idx);
    vq_gather<<<1024, 256, 0, stream>>>(CB, out_idx, out);
}